// Round 3
// baseline (752.111 us; speedup 1.0000x reference)
//
#include <hip/hip_runtime.h>

#define L_RES 2000
#define DF 54
#define WIN 7

typedef short bf16x8 __attribute__((ext_vector_type(8)));
typedef float f32x4 __attribute__((ext_vector_type(4)));

__device__ __forceinline__ unsigned short f2bf(float f) {
    unsigned int u = __float_as_uint(f);
    unsigned int r = (u + 0x7FFFu + ((u >> 16) & 1u)) >> 16;
    return (unsigned short)r;
}

// ---------------- Kernel 1: f = beft @ W_bert + b, 4 residues per block ----------------
__global__ __launch_bounds__(256) void bert_lin4(const float* __restrict__ beft,
                                                 const float* __restrict__ Wb,
                                                 const float* __restrict__ bb,
                                                 float* __restrict__ f) {
    int l0 = blockIdx.x * 4;
    int t = threadIdx.x;
    __shared__ float rows[4 * 1024];
    __shared__ float part[4][4][DF];   // [q][res][n]
    for (int k = t; k < 4096; k += 256) rows[k] = beft[(size_t)l0 * 1024 + k];
    __syncthreads();
    if (t < 216) {
        int q = t / DF, n = t % DF;
        float s0 = 0.f, s1 = 0.f, s2 = 0.f, s3 = 0.f;
        for (int k = q * 256; k < q * 256 + 256; ++k) {
            float wv = Wb[k * DF + n];
            s0 = fmaf(rows[k], wv, s0);
            s1 = fmaf(rows[1024 + k], wv, s1);
            s2 = fmaf(rows[2048 + k], wv, s2);
            s3 = fmaf(rows[3072 + k], wv, s3);
        }
        part[q][0][n] = s0; part[q][1][n] = s1; part[q][2][n] = s2; part[q][3][n] = s3;
    }
    __syncthreads();
    if (t < 216) {
        int r = t / DF, n = t % DF;
        f[(size_t)(l0 + r) * DF + n] =
            part[0][r][n] + part[1][r][n] + part[2][r][n] + part[3][r][n] + bb[n];
    }
}

// ---------------- Kernel 2: window gather + attn x2 + concat, 4 residues (1 wave each) ----------------
__device__ __forceinline__ void attn_layer_w(const float (*in)[DF], float (*out)[DF],
                                             float (*s)[WIN][WIN],
                                             const float* __restrict__ g,
                                             const float* __restrict__ b,
                                             float* mm, float* vv, int lane) {
    for (int idx = lane; idx < 3 * WIN * WIN; idx += 64) {
        int h = idx / 49, r = idx % 49, q = r / WIN, k = r % WIN;
        float sum = 0.f;
        #pragma unroll
        for (int d = 0; d < 18; ++d) sum = fmaf(in[q][h * 18 + d], in[k][h * 18 + d], sum);
        s[h][q][k] = sum;
    }
    __syncthreads();
    for (int idx = lane; idx < 3 * WIN; idx += 64) {
        int h = idx / WIN, q = idx % WIN;
        float mx = s[h][q][0];
        #pragma unroll
        for (int k = 1; k < WIN; ++k) mx = fmaxf(mx, s[h][q][k]);
        float e[WIN], sum = 0.f;
        #pragma unroll
        for (int k = 0; k < WIN; ++k) { e[k] = expf(s[h][q][k] - mx); sum += e[k]; }
        float inv = 1.f / sum;
        #pragma unroll
        for (int k = 0; k < WIN; ++k) s[h][q][k] = e[k] * inv;
    }
    __syncthreads();
    for (int idx = lane; idx < WIN * DF; idx += 64) {
        int q = idx / DF, c = idx % DF, h = c / 18;
        float sum = 0.f;
        #pragma unroll
        for (int k = 0; k < WIN; ++k) sum = fmaf(s[h][q][k], in[k][c], sum);
        out[q][c] = sum;
    }
    __syncthreads();
    for (int q = lane; q < WIN; q += 64) {
        float m = 0.f;
        for (int c = 0; c < DF; ++c) m += out[q][c];
        m *= (1.f / DF);
        float v = 0.f;
        for (int c = 0; c < DF; ++c) { float d0 = out[q][c] - m; v = fmaf(d0, d0, v); }
        v *= (1.f / DF);
        mm[q] = m; vv[q] = rsqrtf(v + 1e-5f);
    }
    __syncthreads();
    for (int idx = lane; idx < WIN * DF; idx += 64) {
        int q = idx / DF, c = idx % DF;
        out[q][c] = (out[q][c] - mm[q]) * vv[q] * g[c] + b[c];
    }
    __syncthreads();
}

__global__ __launch_bounds__(256) void window_attn4(const float* __restrict__ f,
                                                    const float* __restrict__ g1,
                                                    const float* __restrict__ b1,
                                                    const float* __restrict__ g2,
                                                    const float* __restrict__ b2,
                                                    float* __restrict__ cat) {
    int wv = threadIdx.x >> 6, lane = threadIdx.x & 63;
    int l = blockIdx.x * 4 + wv;
    __shared__ float w[4][WIN][DF], o1[4][WIN][DF], o2[4][WIN][DF];
    __shared__ float s[4][3][WIN][WIN];
    __shared__ float mm[4][WIN], vvv[4][WIN];
    bool boundary = (l <= WIN) || (l + WIN >= L_RES);
    for (int idx = lane; idx < WIN * DF; idx += 64) {
        int j = idx / DF, d = idx % DF;
        w[wv][j][d] = boundary ? (j == 0 ? f[(size_t)l * DF + d] : 0.f)
                               : f[(size_t)(l - 4 + j) * DF + d];
    }
    __syncthreads();
    attn_layer_w(w[wv], o1[wv], s[wv], g1, b1, mm[wv], vvv[wv], lane);
    attn_layer_w(o1[wv], o2[wv], s[wv], g2, b2, mm[wv], vvv[wv], lane);
    for (int idx = lane; idx < WIN * DF; idx += 64) {
        int j = idx / DF, d = idx % DF;
        cat[(size_t)l * 756 + j * 108 + d] = w[wv][j][d];
        cat[(size_t)l * 756 + j * 108 + DF + d] = o2[wv][j][d];
    }
}

// ---------------- W1T build: [256][1152] bf16, col = seg*128 + d, zero-padded ----------------
__global__ __launch_bounds__(256) void w1t_build(const float* __restrict__ W1,
                                                 unsigned short* __restrict__ W1T) {
    int idx = blockIdx.x * 256 + threadIdx.x;   // over 256*1152
    int n = idx / 1152, col = idx % 1152;
    int seg = col >> 7, d = col & 127;
    float v = (d < 108) ? W1[(size_t)(seg * 108 + d) * 256 + n] : 0.f;
    W1T[idx] = f2bf(v);
}

// ---------------- transpose + f32->bf16 (for W2) ----------------
__global__ __launch_bounds__(256) void transpose_to_bf16(const float* __restrict__ src,
                                                         unsigned short* __restrict__ dst,
                                                         int M, int N, int Mpad) {
    __shared__ float tile[32][33];
    int m0 = blockIdx.x * 32, n0 = blockIdx.y * 32;
    int c = threadIdx.x % 32, r0 = threadIdx.x / 32;
    #pragma unroll
    for (int rr = 0; rr < 4; ++rr) {
        int r = r0 + rr * 8, m = m0 + r;
        tile[r][c] = (m < M) ? src[(size_t)m * N + n0 + c] : 0.f;
    }
    __syncthreads();
    #pragma unroll
    for (int rr = 0; rr < 4; ++rr) {
        int r = r0 + rr * 8;
        dst[(size_t)(n0 + r) * Mpad + m0 + c] = f2bf(tile[c][r]);
    }
}

// zero bf16 y1 pad rows 2000..2047
__global__ __launch_bounds__(256) void zero_pad_rows(unsigned int* __restrict__ p) {
    int i = blockIdx.x * 256 + threadIdx.x;
    if (i < 196608) p[i] = 0u;
}

// ---------------- Kernel 3: fused conv+pool+GEMM1, 4 residues/block, 9 seg-phases ----------------
#define ASTRIDE 144
__global__ __launch_bounds__(256, 2) void conv_mfma1(
        const float* __restrict__ cat,
        const float* __restrict__ c1w, const float* __restrict__ c1b,
        const float* __restrict__ pa_p,
        const float* __restrict__ c2w, const float* __restrict__ c2b,
        const float* __restrict__ c3w, const float* __restrict__ c3b,
        const unsigned short* __restrict__ W1T, const float* __restrict__ b1v,
        unsigned short* __restrict__ y1) {
    int l0 = blockIdx.x * 4;
    int t = threadIdx.x;
    __shared__ float catl[4 * 756];
    __shared__ float wsh[576];
    __shared__ unsigned short A[128 * ASTRIDE];
    float pa = pa_p[0];
    for (int idx = t; idx < 3024; idx += 256) catl[idx] = cat[(size_t)l0 * 756 + idx];
    for (int idx = t; idx < 576; idx += 256) {
        float v;
        if (idx < 96)       v = c1w[idx];
        else if (idx < 128) v = c1b[idx - 96];
        else if (idx < 288) v = c2w[idx - 128];
        else if (idx < 320) v = c2b[idx - 288];
        else if (idx < 544) v = c3w[idx - 320];
        else                v = c3b[idx - 544];
        wsh[idx] = v;
    }
    // zero pad cols 108..127 once (cols 128..143 never read)
    for (int idx = t; idx < 128 * 20; idx += 256)
        A[(idx / 20) * ASTRIDE + 108 + (idx % 20)] = 0;
    __syncthreads();

    int w = t >> 6, lane = t & 63;
    int n0 = w * 64;
    int arow = lane & 15, kgrp = lane >> 4;
    f32x4 acc[8][4];
    #pragma unroll
    for (int mi = 0; mi < 8; ++mi)
        #pragma unroll
        for (int ni = 0; ni < 4; ++ni) acc[mi][ni] = (f32x4)(0.f);

    for (int s = 0; s < 9; ++s) {
        // ---- conv: one pooled segment for all 128 (res,c) rows, cols 0..107 ----
        #pragma unroll 2
        for (int it = 0; it < 54; ++it) {
            int i = it * 256 + t;
            int d = i % 108, c = (i / 108) % 32, res = i / 3456;
            int row = res * 32 + c;
            float col[WIN];
            #pragma unroll
            for (int h = 0; h < WIN; ++h) col[h] = catl[res * 756 + h * 108 + d];
            float r;
            if (s < 5) {
                float w0 = wsh[c * 3], w1 = wsh[c * 3 + 1], w2 = wsh[c * 3 + 2];
                float bb = wsh[96 + c];
                float mx = -1e30f;
                #pragma unroll
                for (int j = 0; j < 3; ++j) {
                    int h = s + j;
                    float sum = bb;
                    if (h >= 1) sum = fmaf(w0, col[h - 1], sum);
                    sum = fmaf(w1, col[h], sum);
                    if (h <= 5) sum = fmaf(w2, col[h + 1], sum);
                    float v = sum >= 0.f ? sum : pa * sum;
                    mx = fmaxf(mx, v);
                }
                r = mx;
            } else if (s < 8) {
                int p0 = s - 5;
                float bb = wsh[288 + c];
                float mx = -1e30f;
                #pragma unroll
                for (int j = 0; j < 5; ++j) {
                    int h = p0 + j;
                    float sum = bb;
                    #pragma unroll
                    for (int x = 0; x < 5; ++x) {
                        int hh = h + x - 2;
                        if (hh >= 0 && hh <= 6) sum = fmaf(wsh[128 + c * 5 + x], col[hh], sum);
                    }
                    mx = fmaxf(mx, sum);
                }
                r = fmaxf(mx, 0.f);
            } else {
                float bb = wsh[544 + c];
                float mx = -1e30f;
                #pragma unroll
                for (int h = 0; h < WIN; ++h) {
                    float sum = bb;
                    #pragma unroll
                    for (int x = 0; x < 7; ++x) {
                        int hh = h + x - 3;
                        if (hh >= 0 && hh <= 6) sum = fmaf(wsh[320 + c * 7 + x], col[hh], sum);
                    }
                    mx = fmaxf(mx, sum);
                }
                r = fmaxf(mx, 0.f);
            }
            A[row * ASTRIDE + d] = f2bf(r);
        }
        __syncthreads();
        // ---- MFMA: 4 K-steps over this 128-col chunk ----
        #pragma unroll
        for (int kk = 0; kk < 4; ++kk) {
            int ko = kk * 32 + kgrp * 8;
            bf16x8 a[8], b[4];
            #pragma unroll
            for (int mi = 0; mi < 8; ++mi)
                a[mi] = *(const bf16x8*)&A[(mi * 16 + arow) * ASTRIDE + ko];
            #pragma unroll
            for (int ni = 0; ni < 4; ++ni)
                b[ni] = *(const bf16x8*)&W1T[(size_t)(n0 + ni * 16 + arow) * 1152 + s * 128 + ko];
            #pragma unroll
            for (int mi = 0; mi < 8; ++mi)
                #pragma unroll
                for (int ni = 0; ni < 4; ++ni)
                    acc[mi][ni] = __builtin_amdgcn_mfma_f32_16x16x32_bf16(a[mi], b[ni], acc[mi][ni], 0, 0, 0);
        }
        __syncthreads();
    }
    // ---- epilogue: bias + bf16 + write y1[(l0+res)][c*256+n] ----
    #pragma unroll
    for (int ni = 0; ni < 4; ++ni) {
        int n = n0 + ni * 16 + arow;
        float bias = b1v[n];
        #pragma unroll
        for (int mi = 0; mi < 8; ++mi)
            #pragma unroll
            for (int r = 0; r < 4; ++r) {
                int row = mi * 16 + kgrp * 4 + r;
                y1[(size_t)(l0 + (row >> 5)) * 8192 + (row & 31) * 256 + n] =
                    f2bf(acc[mi][ni][r] + bias);
            }
    }
}

// ---------------- Kernel 4: gemm2 partials ----------------
__global__ __launch_bounds__(256) void gemm2_mfma(const unsigned short* __restrict__ y1,
                                                  const unsigned short* __restrict__ W2T,
                                                  float* __restrict__ part) {
    int m0 = blockIdx.x * 32;
    int s = blockIdx.y;
    int t = threadIdx.x, w = t >> 6, lane = t & 63;
    int n0 = w * 64;
    int arow = lane & 15, kgrp = lane >> 4;
    f32x4 acc[2][4];
    #pragma unroll
    for (int mi = 0; mi < 2; ++mi)
        #pragma unroll
        for (int ni = 0; ni < 4; ++ni) acc[mi][ni] = (f32x4)(0.f);
    int kbase = s * 1024;
    for (int kk = 0; kk < 32; ++kk) {
        int k0 = kbase + kk * 32 + kgrp * 8;
        bf16x8 a0 = *(const bf16x8*)&y1[(size_t)(m0 + arow) * 8192 + k0];
        bf16x8 a1 = *(const bf16x8*)&y1[(size_t)(m0 + 16 + arow) * 8192 + k0];
        bf16x8 b[4];
        #pragma unroll
        for (int ni = 0; ni < 4; ++ni)
            b[ni] = *(const bf16x8*)&W2T[(size_t)(n0 + ni * 16 + arow) * 8192 + k0];
        #pragma unroll
        for (int ni = 0; ni < 4; ++ni) {
            acc[0][ni] = __builtin_amdgcn_mfma_f32_16x16x32_bf16(a0, b[ni], acc[0][ni], 0, 0, 0);
            acc[1][ni] = __builtin_amdgcn_mfma_f32_16x16x32_bf16(a1, b[ni], acc[1][ni], 0, 0, 0);
        }
    }
    #pragma unroll
    for (int ni = 0; ni < 4; ++ni) {
        int n = n0 + ni * 16 + arow;
        #pragma unroll
        for (int mi = 0; mi < 2; ++mi)
            #pragma unroll
            for (int r = 0; r < 4; ++r) {
                int row = m0 + mi * 16 + kgrp * 4 + r;
                part[((size_t)s * 2048 + row) * 256 + n] = acc[mi][ni][r];
            }
    }
}

// ---------------- Kernel 5: reduce partials + bias + leaky ----------------
__global__ __launch_bounds__(256) void reduce2(const float* __restrict__ part,
                                               const float* __restrict__ b2v,
                                               float* __restrict__ out) {
    int l = blockIdx.x, n = threadIdx.x;
    float sum = b2v[n];
    #pragma unroll
    for (int s = 0; s < 8; ++s) sum += part[((size_t)s * 2048 + l) * 256 + n];
    out[(size_t)l * 256 + n] = sum >= 0.f ? sum : 0.01f * sum;
}

extern "C" void kernel_launch(void* const* d_in, const int* in_sizes, int n_in,
                              void* d_out, int out_size, void* d_ws, size_t ws_size,
                              hipStream_t stream) {
    const float* beft = (const float*)d_in[0];
    const float* Wb  = (const float*)d_in[4];
    const float* bb  = (const float*)d_in[5];
    const float* g1  = (const float*)d_in[6];
    const float* b1  = (const float*)d_in[7];
    const float* g2  = (const float*)d_in[8];
    const float* b2  = (const float*)d_in[9];
    const float* c1w = (const float*)d_in[10];
    const float* c1b = (const float*)d_in[11];
    const float* pa  = (const float*)d_in[12];
    const float* c2w = (const float*)d_in[13];
    const float* c2b = (const float*)d_in[14];
    const float* c3w = (const float*)d_in[15];
    const float* c3b = (const float*)d_in[16];
    const float* W1  = (const float*)d_in[17];
    const float* b1v = (const float*)d_in[18];
    const float* W2  = (const float*)d_in[19];
    const float* b2v = (const float*)d_in[20];
    float* out = (float*)d_out;
    char* ws = (char*)d_ws;

    float*          f    = (float*)(ws + 0);                 // 432,000 B
    float*          cat  = (float*)(ws + 524288);            // 6,048,000 B
    unsigned short* W1T  = (unsigned short*)(ws + 6815744);  // 256*1152*2 = 589,824 B
    unsigned short* W2T  = (unsigned short*)(ws + 7602176);  // 4,194,304 B
    unsigned short* y1   = (unsigned short*)(ws + 11796480); // 2048*8192*2 = 33,554,432 B
    float*          part = (float*)(ws + 45350912);          // 16,777,216 B -> 62.1 MB total

    bert_lin4<<<500, 256, 0, stream>>>(beft, Wb, bb, f);
    window_attn4<<<500, 256, 0, stream>>>(f, g1, b1, g2, b2, cat);
    w1t_build<<<1152, 256, 0, stream>>>(W1, W1T);
    transpose_to_bf16<<<dim3(256, 8), 256, 0, stream>>>(W2, W2T, 8192, 256, 8192);
    zero_pad_rows<<<768, 256, 0, stream>>>((unsigned int*)(y1 + (size_t)2000 * 8192));
    conv_mfma1<<<500, 256, 0, stream>>>(cat, c1w, c1b, pa, c2w, c2b, c3w, c3b,
                                        W1T, b1v, y1);
    gemm2_mfma<<<dim3(64, 8), 256, 0, stream>>>(y1, W2T, part);
    reduce2<<<L_RES, 256, 0, stream>>>(part, b2v, out);
}

// Round 4
// 209.520 us; speedup vs baseline: 3.5897x; 3.5897x over previous
//
#include <hip/hip_runtime.h>

#define L_RES 2000
#define DF 54
#define WIN 7

typedef short bf16x8 __attribute__((ext_vector_type(8)));
typedef float f32x4 __attribute__((ext_vector_type(4)));
typedef unsigned short ushort8v __attribute__((ext_vector_type(8)));

__device__ __forceinline__ unsigned short f2bf(float f) {
    unsigned int u = __float_as_uint(f);
    unsigned int r = (u + 0x7FFFu + ((u >> 16) & 1u)) >> 16;
    return (unsigned short)r;
}

// ---------------- Kernel 1: f = beft @ W_bert + b, 4 residues per block ----------------
__global__ __launch_bounds__(256) void bert_lin4(const float* __restrict__ beft,
                                                 const float* __restrict__ Wb,
                                                 const float* __restrict__ bb,
                                                 float* __restrict__ f) {
    int l0 = blockIdx.x * 4;
    int t = threadIdx.x;
    __shared__ float rows[4 * 1024];
    __shared__ float part[4][4][DF];   // [q][res][n]
    for (int k = t; k < 4096; k += 256) rows[k] = beft[(size_t)l0 * 1024 + k];
    __syncthreads();
    if (t < 216) {
        int q = t / DF, n = t % DF;
        float s0 = 0.f, s1 = 0.f, s2 = 0.f, s3 = 0.f;
        for (int k = q * 256; k < q * 256 + 256; ++k) {
            float wv = Wb[k * DF + n];
            s0 = fmaf(rows[k], wv, s0);
            s1 = fmaf(rows[1024 + k], wv, s1);
            s2 = fmaf(rows[2048 + k], wv, s2);
            s3 = fmaf(rows[3072 + k], wv, s3);
        }
        part[q][0][n] = s0; part[q][1][n] = s1; part[q][2][n] = s2; part[q][3][n] = s3;
    }
    __syncthreads();
    if (t < 216) {
        int r = t / DF, n = t % DF;
        f[(size_t)(l0 + r) * DF + n] =
            part[0][r][n] + part[1][r][n] + part[2][r][n] + part[3][r][n] + bb[n];
    }
}

// ---------------- Kernel 2: window gather + attn x2 + concat, 4 residues (1 wave each) ----------------
__device__ __forceinline__ void attn_layer_w(const float (*in)[DF], float (*out)[DF],
                                             float (*s)[WIN][WIN],
                                             const float* __restrict__ g,
                                             const float* __restrict__ b,
                                             float* mm, float* vv, int lane) {
    for (int idx = lane; idx < 3 * WIN * WIN; idx += 64) {
        int h = idx / 49, r = idx % 49, q = r / WIN, k = r % WIN;
        float sum = 0.f;
        #pragma unroll
        for (int d = 0; d < 18; ++d) sum = fmaf(in[q][h * 18 + d], in[k][h * 18 + d], sum);
        s[h][q][k] = sum;
    }
    __syncthreads();
    for (int idx = lane; idx < 3 * WIN; idx += 64) {
        int h = idx / WIN, q = idx % WIN;
        float mx = s[h][q][0];
        #pragma unroll
        for (int k = 1; k < WIN; ++k) mx = fmaxf(mx, s[h][q][k]);
        float e[WIN], sum = 0.f;
        #pragma unroll
        for (int k = 0; k < WIN; ++k) { e[k] = expf(s[h][q][k] - mx); sum += e[k]; }
        float inv = 1.f / sum;
        #pragma unroll
        for (int k = 0; k < WIN; ++k) s[h][q][k] = e[k] * inv;
    }
    __syncthreads();
    for (int idx = lane; idx < WIN * DF; idx += 64) {
        int q = idx / DF, c = idx % DF, h = c / 18;
        float sum = 0.f;
        #pragma unroll
        for (int k = 0; k < WIN; ++k) sum = fmaf(s[h][q][k], in[k][c], sum);
        out[q][c] = sum;
    }
    __syncthreads();
    for (int q = lane; q < WIN; q += 64) {
        float m = 0.f;
        for (int c = 0; c < DF; ++c) m += out[q][c];
        m *= (1.f / DF);
        float v = 0.f;
        for (int c = 0; c < DF; ++c) { float d0 = out[q][c] - m; v = fmaf(d0, d0, v); }
        v *= (1.f / DF);
        mm[q] = m; vv[q] = rsqrtf(v + 1e-5f);
    }
    __syncthreads();
    for (int idx = lane; idx < WIN * DF; idx += 64) {
        int q = idx / DF, c = idx % DF;
        out[q][c] = (out[q][c] - mm[q]) * vv[q] * g[c] + b[c];
    }
    __syncthreads();
}

__global__ __launch_bounds__(256) void window_attn4(const float* __restrict__ f,
                                                    const float* __restrict__ g1,
                                                    const float* __restrict__ b1,
                                                    const float* __restrict__ g2,
                                                    const float* __restrict__ b2,
                                                    float* __restrict__ cat) {
    int wv = threadIdx.x >> 6, lane = threadIdx.x & 63;
    int l = blockIdx.x * 4 + wv;
    __shared__ float w[4][WIN][DF], o1[4][WIN][DF], o2[4][WIN][DF];
    __shared__ float s[4][3][WIN][WIN];
    __shared__ float mm[4][WIN], vvv[4][WIN];
    bool boundary = (l <= WIN) || (l + WIN >= L_RES);
    for (int idx = lane; idx < WIN * DF; idx += 64) {
        int j = idx / DF, d = idx % DF;
        w[wv][j][d] = boundary ? (j == 0 ? f[(size_t)l * DF + d] : 0.f)
                               : f[(size_t)(l - 4 + j) * DF + d];
    }
    __syncthreads();
    attn_layer_w(w[wv], o1[wv], s[wv], g1, b1, mm[wv], vvv[wv], lane);
    attn_layer_w(o1[wv], o2[wv], s[wv], g2, b2, mm[wv], vvv[wv], lane);
    for (int idx = lane; idx < WIN * DF; idx += 64) {
        int j = idx / DF, d = idx % DF;
        cat[(size_t)l * 756 + j * 108 + d] = w[wv][j][d];
        cat[(size_t)l * 756 + j * 108 + DF + d] = o2[wv][j][d];
    }
}

// ---------------- transpose + f32->bf16: dst[n][m], rows m>=M zero-padded ----------------
__global__ __launch_bounds__(256) void transpose_to_bf16(const float* __restrict__ src,
                                                         unsigned short* __restrict__ dst,
                                                         int M, int N, int Mpad) {
    __shared__ float tile[32][33];
    int m0 = blockIdx.x * 32, n0 = blockIdx.y * 32;
    int c = threadIdx.x % 32, r0 = threadIdx.x / 32;
    #pragma unroll
    for (int rr = 0; rr < 4; ++rr) {
        int r = r0 + rr * 8, m = m0 + r;
        tile[r][c] = (m < M) ? src[(size_t)m * N + n0 + c] : 0.f;
    }
    __syncthreads();
    #pragma unroll
    for (int rr = 0; rr < 4; ++rr) {
        int r = r0 + rr * 8;
        dst[(size_t)(n0 + r) * Mpad + m0 + c] = f2bf(tile[c][r]);
    }
}

// zero bf16 y1 pad rows 2000..2047
__global__ __launch_bounds__(256) void zero_pad_rows(unsigned int* __restrict__ p) {
    int i = blockIdx.x * 256 + threadIdx.x;
    if (i < 196608) p[i] = 0u;
}

// ---------------- Kernel 3a: conv+pool -> Apool[nres*32][1024] bf16 (chunk-local rows) ----------------
__global__ __launch_bounds__(256) void conv_pool(
        const float* __restrict__ cat,
        const float* __restrict__ c1w, const float* __restrict__ c1b,
        const float* __restrict__ pa_p,
        const float* __restrict__ c2w, const float* __restrict__ c2b,
        const float* __restrict__ c3w, const float* __restrict__ c3b,
        unsigned short* __restrict__ Ap, int lbase) {
    int l = lbase + blockIdx.x;
    int t = threadIdx.x;
    __shared__ float catl[756];
    for (int i = t; i < 756; i += 256) catl[i] = cat[(size_t)l * 756 + i];
    __syncthreads();
    float pa = pa_p[0];
    size_t rowbase = (size_t)blockIdx.x * 32;
    for (int idx = t; idx < 3456; idx += 256) {
        int c = idx / 108, d = idx - c * 108;
        unsigned short* Arow = Ap + (rowbase + c) * 1024;
        float col[WIN];
        #pragma unroll
        for (int h = 0; h < WIN; ++h) col[h] = catl[h * 108 + d];
        // branch 1: k=3, prelu, pool3 -> 5 outputs
        {
            float w0 = c1w[c * 3], w1 = c1w[c * 3 + 1], w2 = c1w[c * 3 + 2], bb = c1b[c];
            float v[WIN];
            #pragma unroll
            for (int h = 0; h < WIN; ++h) {
                float sum = bb;
                if (h >= 1) sum = fmaf(w0, col[h - 1], sum);
                sum = fmaf(w1, col[h], sum);
                if (h <= 5) sum = fmaf(w2, col[h + 1], sum);
                v[h] = sum >= 0.f ? sum : pa * sum;
            }
            #pragma unroll
            for (int p = 0; p < 5; ++p)
                Arow[p * 108 + d] = f2bf(fmaxf(fmaxf(v[p], v[p + 1]), v[p + 2]));
        }
        // branch 2: k=5, relu, pool5 -> 3 outputs
        {
            float wg[5], bb = c2b[c];
            #pragma unroll
            for (int x = 0; x < 5; ++x) wg[x] = c2w[c * 5 + x];
            float v[WIN];
            #pragma unroll
            for (int h = 0; h < WIN; ++h) {
                float sum = bb;
                #pragma unroll
                for (int x = 0; x < 5; ++x) {
                    int hh = h + x - 2;
                    if (hh >= 0 && hh <= 6) sum = fmaf(wg[x], col[hh], sum);
                }
                v[h] = fmaxf(sum, 0.f);
            }
            #pragma unroll
            for (int p = 0; p < 3; ++p) {
                float mx = v[p];
                #pragma unroll
                for (int r = 1; r < 5; ++r) mx = fmaxf(mx, v[p + r]);
                Arow[540 + p * 108 + d] = f2bf(mx);
            }
        }
        // branch 3: k=7, relu, pool7 -> 1 output
        {
            float wg[7], bb = c3b[c];
            #pragma unroll
            for (int x = 0; x < 7; ++x) wg[x] = c3w[c * 7 + x];
            float mx = 0.f;
            #pragma unroll
            for (int h = 0; h < WIN; ++h) {
                float sum = bb;
                #pragma unroll
                for (int x = 0; x < 7; ++x) {
                    int hh = h + x - 3;
                    if (hh >= 0 && hh <= 6) sum = fmaf(wg[x], col[hh], sum);
                }
                mx = fmaxf(mx, fmaxf(sum, 0.f));
            }
            Arow[864 + d] = f2bf(mx);
        }
    }
    // zero K-pad cols 972..1023
    for (int i = t; i < 832; i += 256) {
        int r = i / 26, q = i - r * 26;
        *(unsigned int*)&Ap[(rowbase + r) * 1024 + 972 + q * 2] = 0u;
    }
}

// ---------------- Tiled MFMA GEMM: C[128x128] per block, BK=64, XOR-swizzled LDS ----------------
// A: [Mrows][lda] bf16 (row-major), B: [256][ldb] bf16 (n-major). K-offset = blockIdx.z*1024.
// EPI_BF16: outB[(outRowBase+m)*256+n] = bf16(acc + bias[n]); else outF[(z*2048+m)*256+n] = acc.
template<bool EPI_BF16>
__global__ __launch_bounds__(256) void gemm_tile(
        const unsigned short* __restrict__ A, long lda,
        const unsigned short* __restrict__ B, long ldb,
        int nk, const float* __restrict__ bias,
        unsigned short* __restrict__ outB, float* __restrict__ outF,
        long outRowBase) {
    __shared__ unsigned short ldsA[128 * 64];
    __shared__ unsigned short ldsB[128 * 64];
    int t = threadIdx.x, w = t >> 6, lane = t & 63;
    int m0 = blockIdx.x * 128, n0 = blockIdx.y * 128;
    long koff = (long)blockIdx.z * 1024;
    A += koff; B += koff;
    int wr = w >> 1, wc = w & 1;
    int arow = lane & 15, kgrp = lane >> 4;

    const unsigned short* aS[4]; const unsigned short* bS[4];
    int aD[4];
    #pragma unroll
    for (int j = 0; j < 4; ++j) {
        int s = j * 256 + t, r = s >> 3, c = s & 7;
        aS[j] = A + (size_t)(m0 + r) * lda + c * 8;
        bS[j] = B + (size_t)(n0 + r) * ldb + c * 8;
        aD[j] = r * 64 + ((c ^ (r & 7)) * 8);
    }
    f32x4 acc[4][4];
    #pragma unroll
    for (int mi = 0; mi < 4; ++mi)
        #pragma unroll
        for (int ni = 0; ni < 4; ++ni) acc[mi][ni] = (f32x4)(0.f);

    ushort8v va[4], vb[4];
    #pragma unroll
    for (int j = 0; j < 4; ++j) { va[j] = *(const ushort8v*)(aS[j]); vb[j] = *(const ushort8v*)(bS[j]); }

    for (int ks = 0; ks < nk; ++ks) {
        __syncthreads();
        #pragma unroll
        for (int j = 0; j < 4; ++j) {
            *(ushort8v*)&ldsA[aD[j]] = va[j];
            *(ushort8v*)&ldsB[aD[j]] = vb[j];
        }
        __syncthreads();
        if (ks + 1 < nk) {
            #pragma unroll
            for (int j = 0; j < 4; ++j) {
                va[j] = *(const ushort8v*)(aS[j] + (ks + 1) * 64);
                vb[j] = *(const ushort8v*)(bS[j] + (ks + 1) * 64);
            }
        }
        #pragma unroll
        for (int kk = 0; kk < 2; ++kk) {
            int chunk = kk * 4 + kgrp;
            bf16x8 af[4], bf[4];
            #pragma unroll
            for (int mi = 0; mi < 4; ++mi) {
                int rl = wr * 64 + mi * 16 + arow;
                af[mi] = *(const bf16x8*)&ldsA[rl * 64 + ((chunk ^ (rl & 7)) * 8)];
            }
            #pragma unroll
            for (int ni = 0; ni < 4; ++ni) {
                int rl = wc * 64 + ni * 16 + arow;
                bf[ni] = *(const bf16x8*)&ldsB[rl * 64 + ((chunk ^ (rl & 7)) * 8)];
            }
            #pragma unroll
            for (int mi = 0; mi < 4; ++mi)
                #pragma unroll
                for (int ni = 0; ni < 4; ++ni)
                    acc[mi][ni] = __builtin_amdgcn_mfma_f32_16x16x32_bf16(af[mi], bf[ni], acc[mi][ni], 0, 0, 0);
        }
    }
    #pragma unroll
    for (int ni = 0; ni < 4; ++ni) {
        int n = n0 + wc * 64 + ni * 16 + arow;
        float bv = EPI_BF16 ? bias[n] : 0.f;
        #pragma unroll
        for (int mi = 0; mi < 4; ++mi)
            #pragma unroll
            for (int r = 0; r < 4; ++r) {
                long m = m0 + wr * 64 + mi * 16 + kgrp * 4 + r;
                if (EPI_BF16)
                    outB[(outRowBase + m) * 256 + n] = f2bf(acc[mi][ni][r] + bv);
                else
                    outF[((long)blockIdx.z * 2048 + m) * 256 + n] = acc[mi][ni][r];
            }
    }
}

// ---------------- reduce partials + bias + leaky ----------------
__global__ __launch_bounds__(256) void reduce2(const float* __restrict__ part,
                                               const float* __restrict__ b2v,
                                               float* __restrict__ out) {
    int l = blockIdx.x, n = threadIdx.x;
    float sum = b2v[n];
    #pragma unroll
    for (int s = 0; s < 8; ++s) sum += part[((size_t)s * 2048 + l) * 256 + n];
    out[(size_t)l * 256 + n] = sum >= 0.f ? sum : 0.01f * sum;
}

extern "C" void kernel_launch(void* const* d_in, const int* in_sizes, int n_in,
                              void* d_out, int out_size, void* d_ws, size_t ws_size,
                              hipStream_t stream) {
    const float* beft = (const float*)d_in[0];
    const float* Wb  = (const float*)d_in[4];
    const float* bb  = (const float*)d_in[5];
    const float* g1  = (const float*)d_in[6];
    const float* b1  = (const float*)d_in[7];
    const float* g2  = (const float*)d_in[8];
    const float* b2  = (const float*)d_in[9];
    const float* c1w = (const float*)d_in[10];
    const float* c1b = (const float*)d_in[11];
    const float* pa  = (const float*)d_in[12];
    const float* c2w = (const float*)d_in[13];
    const float* c2b = (const float*)d_in[14];
    const float* c3w = (const float*)d_in[15];
    const float* c3b = (const float*)d_in[16];
    const float* W1  = (const float*)d_in[17];
    const float* b1v = (const float*)d_in[18];
    const float* W2  = (const float*)d_in[19];
    const float* b2v = (const float*)d_in[20];
    float* out = (float*)d_out;
    char* ws = (char*)d_ws;

    // layout (part overlays f+cat region; temporally disjoint):
    float*          f    = (float*)(ws + 0);          // 432,000 B  [dead after attn]
    float*          cat  = (float*)(ws + 524288);     // 6,048,000 B [dead after conv]
    float*          part = (float*)(ws + 0);          // 16,777,216 B [gemm2 phase only]
    unsigned short* W1T  = (unsigned short*)(ws + 16777216);  // 256*1024*2
    unsigned short* W2T  = (unsigned short*)(ws + 17301504);  // 256*8192*2
    unsigned short* y1   = (unsigned short*)(ws + 21495808);  // 2048*8192*2
    unsigned short* Ap   = (unsigned short*)(ws + 55050240);  // adaptive chunk

    long avail = (long)ws_size - 55050240L;
    long tpc = avail / (128L * 1024L * 2L);    // M-tiles per chunk (128 rows x 1024 cols bf16)
    if (tpc < 1) tpc = 1;                      // (ws >= 62.1MB proven -> >= 27)
    if (tpc > 500) tpc = 500;

    bert_lin4<<<500, 256, 0, stream>>>(beft, Wb, bb, f);
    window_attn4<<<500, 256, 0, stream>>>(f, g1, b1, g2, b2, cat);
    transpose_to_bf16<<<dim3(32, 8), 256, 0, stream>>>(W1, W1T, 972, 256, 1024);
    transpose_to_bf16<<<dim3(256, 8), 256, 0, stream>>>(W2, W2T, 8192, 256, 8192);
    zero_pad_rows<<<768, 256, 0, stream>>>((unsigned int*)(y1 + (size_t)2000 * 8192));

    for (long t0 = 0; t0 < 500; t0 += tpc) {
        long nt = (500 - t0 < tpc) ? (500 - t0) : tpc;
        conv_pool<<<(int)(nt * 4), 256, 0, stream>>>(cat, c1w, c1b, pa, c2w, c2b,
                                                     c3w, c3b, Ap, (int)(t0 * 4));
        gemm_tile<true><<<dim3((int)nt, 2, 1), 256, 0, stream>>>(
            Ap, 1024, W1T, 1024, 16, b1v, y1, nullptr, t0 * 128);
    }
    gemm_tile<false><<<dim3(16, 2, 8), 256, 0, stream>>>(
        y1, 8192, W2T, 8192, 16, nullptr, nullptr, part, 0);
    reduce2<<<L_RES, 256, 0, stream>>>(part, b2v, out);
}

// Round 5
// 190.673 us; speedup vs baseline: 3.9445x; 1.0988x over previous
//
#include <hip/hip_runtime.h>

#define L_RES 2000
#define DF 54
#define WIN 7

typedef short bf16x8 __attribute__((ext_vector_type(8)));
typedef float f32x4 __attribute__((ext_vector_type(4)));
typedef unsigned short ushort8v __attribute__((ext_vector_type(8)));

__device__ __forceinline__ unsigned short f2bf(float f) {
    unsigned int u = __float_as_uint(f);
    unsigned int r = (u + 0x7FFFu + ((u >> 16) & 1u)) >> 16;
    return (unsigned short)r;
}
__device__ __forceinline__ float bf2f(unsigned short h) {
    return __uint_as_float(((unsigned int)h) << 16);
}

// ---------------- bert stage a: split beft into A2 = [hi | lo | hi], K=3072, 2048 rows ----------------
__global__ __launch_bounds__(256) void split_beft(const float* __restrict__ beft,
                                                  unsigned short* __restrict__ A2) {
    int l = blockIdx.x;
    int t = threadIdx.x;
    unsigned short* row = A2 + (size_t)l * 3072;
    for (int k = t; k < 1024; k += 256) {
        unsigned short hi = 0, lo = 0;
        if (l < L_RES) {
            float x = beft[(size_t)l * 1024 + k];
            hi = f2bf(x);
            lo = f2bf(x - bf2f(hi));
        }
        row[k] = hi;
        row[1024 + k] = lo;
        row[2048 + k] = hi;
    }
}

// ---------------- bert stage b: B2T[64][3072]: segs {hi,hi,lo} of Wb^T ----------------
__global__ __launch_bounds__(256) void b2t_build(const float* __restrict__ Wb,
                                                 unsigned short* __restrict__ B2T) {
    int idx = blockIdx.x * 256 + threadIdx.x;   // 64*3072 = 196608
    int n = idx / 3072, col = idx % 3072;
    int seg = col >> 10, k = col & 1023;
    unsigned short r = 0;
    if (n < DF) {
        float v = Wb[(size_t)k * DF + n];
        unsigned short hi = f2bf(v);
        r = (seg < 2) ? hi : f2bf(v - bf2f(hi));
    }
    B2T[idx] = r;
}

// ---------------- bert stage c: MFMA GEMM M=2048 N=64 K=3072 -> f fp32 ----------------
__global__ __launch_bounds__(256) void bert_mfma(const unsigned short* __restrict__ A2,
                                                 const unsigned short* __restrict__ B2T,
                                                 const float* __restrict__ bb,
                                                 float* __restrict__ f) {
    __shared__ unsigned short ldsA[128 * 64];
    __shared__ unsigned short ldsB[64 * 64];
    int t = threadIdx.x, w = t >> 6, lane = t & 63;
    int m0 = blockIdx.x * 128;
    int wr = w >> 1, wc = w & 1;
    int arow = lane & 15, kgrp = lane >> 4;

    const unsigned short* aS[4]; const unsigned short* bS[2];
    int aD[4], bD[2];
    #pragma unroll
    for (int j = 0; j < 4; ++j) {
        int s = j * 256 + t, r = s >> 3, c = s & 7;
        aS[j] = A2 + (size_t)(m0 + r) * 3072 + c * 8;
        aD[j] = r * 64 + ((c ^ (r & 7)) * 8);
    }
    #pragma unroll
    for (int j = 0; j < 2; ++j) {
        int s = j * 256 + t, r = s >> 3, c = s & 7;
        bS[j] = B2T + (size_t)r * 3072 + c * 8;
        bD[j] = r * 64 + ((c ^ (r & 7)) * 8);
    }
    f32x4 acc[4][2];
    #pragma unroll
    for (int mi = 0; mi < 4; ++mi)
        #pragma unroll
        for (int ni = 0; ni < 2; ++ni) acc[mi][ni] = (f32x4)(0.f);

    ushort8v va[4], vb[2];
    #pragma unroll
    for (int j = 0; j < 4; ++j) va[j] = *(const ushort8v*)(aS[j]);
    #pragma unroll
    for (int j = 0; j < 2; ++j) vb[j] = *(const ushort8v*)(bS[j]);

    for (int ks = 0; ks < 48; ++ks) {
        __syncthreads();
        #pragma unroll
        for (int j = 0; j < 4; ++j) *(ushort8v*)&ldsA[aD[j]] = va[j];
        #pragma unroll
        for (int j = 0; j < 2; ++j) *(ushort8v*)&ldsB[bD[j]] = vb[j];
        __syncthreads();
        if (ks + 1 < 48) {
            #pragma unroll
            for (int j = 0; j < 4; ++j) va[j] = *(const ushort8v*)(aS[j] + (ks + 1) * 64);
            #pragma unroll
            for (int j = 0; j < 2; ++j) vb[j] = *(const ushort8v*)(bS[j] + (ks + 1) * 64);
        }
        #pragma unroll
        for (int kk = 0; kk < 2; ++kk) {
            int chunk = kk * 4 + kgrp;
            bf16x8 af[4], bfr[2];
            #pragma unroll
            for (int mi = 0; mi < 4; ++mi) {
                int rl = wr * 64 + mi * 16 + arow;
                af[mi] = *(const bf16x8*)&ldsA[rl * 64 + ((chunk ^ (rl & 7)) * 8)];
            }
            #pragma unroll
            for (int ni = 0; ni < 2; ++ni) {
                int rl = wc * 32 + ni * 16 + arow;
                bfr[ni] = *(const bf16x8*)&ldsB[rl * 64 + ((chunk ^ (rl & 7)) * 8)];
            }
            #pragma unroll
            for (int mi = 0; mi < 4; ++mi)
                #pragma unroll
                for (int ni = 0; ni < 2; ++ni)
                    acc[mi][ni] = __builtin_amdgcn_mfma_f32_16x16x32_bf16(af[mi], bfr[ni], acc[mi][ni], 0, 0, 0);
        }
    }
    #pragma unroll
    for (int ni = 0; ni < 2; ++ni) {
        int n = wc * 32 + ni * 16 + arow;
        if (n < DF) {
            float bv = bb[n];
            #pragma unroll
            for (int mi = 0; mi < 4; ++mi)
                #pragma unroll
                for (int r = 0; r < 4; ++r) {
                    int m = m0 + wr * 64 + mi * 16 + kgrp * 4 + r;
                    if (m < L_RES) f[(size_t)m * DF + n] = acc[mi][ni][r] + bv;
                }
        }
    }
}

// ---------------- window gather + attn x2 + concat, 4 residues (1 wave each) ----------------
__device__ __forceinline__ void attn_layer_w(const float (*in)[DF], float (*out)[DF],
                                             float (*s)[WIN][WIN],
                                             const float* __restrict__ g,
                                             const float* __restrict__ b,
                                             float* mm, float* vv, int lane) {
    for (int idx = lane; idx < 3 * WIN * WIN; idx += 64) {
        int h = idx / 49, r = idx % 49, q = r / WIN, k = r % WIN;
        float sum = 0.f;
        #pragma unroll
        for (int d = 0; d < 18; ++d) sum = fmaf(in[q][h * 18 + d], in[k][h * 18 + d], sum);
        s[h][q][k] = sum;
    }
    __syncthreads();
    for (int idx = lane; idx < 3 * WIN; idx += 64) {
        int h = idx / WIN, q = idx % WIN;
        float mx = s[h][q][0];
        #pragma unroll
        for (int k = 1; k < WIN; ++k) mx = fmaxf(mx, s[h][q][k]);
        float e[WIN], sum = 0.f;
        #pragma unroll
        for (int k = 0; k < WIN; ++k) { e[k] = expf(s[h][q][k] - mx); sum += e[k]; }
        float inv = 1.f / sum;
        #pragma unroll
        for (int k = 0; k < WIN; ++k) s[h][q][k] = e[k] * inv;
    }
    __syncthreads();
    for (int idx = lane; idx < WIN * DF; idx += 64) {
        int q = idx / DF, c = idx % DF, h = c / 18;
        float sum = 0.f;
        #pragma unroll
        for (int k = 0; k < WIN; ++k) sum = fmaf(s[h][q][k], in[k][c], sum);
        out[q][c] = sum;
    }
    __syncthreads();
    for (int q = lane; q < WIN; q += 64) {
        float m = 0.f;
        for (int c = 0; c < DF; ++c) m += out[q][c];
        m *= (1.f / DF);
        float v = 0.f;
        for (int c = 0; c < DF; ++c) { float d0 = out[q][c] - m; v = fmaf(d0, d0, v); }
        v *= (1.f / DF);
        mm[q] = m; vv[q] = rsqrtf(v + 1e-5f);
    }
    __syncthreads();
    for (int idx = lane; idx < WIN * DF; idx += 64) {
        int q = idx / DF, c = idx % DF;
        out[q][c] = (out[q][c] - mm[q]) * vv[q] * g[c] + b[c];
    }
    __syncthreads();
}

__global__ __launch_bounds__(256) void window_attn4(const float* __restrict__ f,
                                                    const float* __restrict__ g1,
                                                    const float* __restrict__ b1,
                                                    const float* __restrict__ g2,
                                                    const float* __restrict__ b2,
                                                    float* __restrict__ cat) {
    int wv = threadIdx.x >> 6, lane = threadIdx.x & 63;
    int l = blockIdx.x * 4 + wv;
    __shared__ float w[4][WIN][DF], o1[4][WIN][DF], o2[4][WIN][DF];
    __shared__ float s[4][3][WIN][WIN];
    __shared__ float mm[4][WIN], vvv[4][WIN];
    bool boundary = (l <= WIN) || (l + WIN >= L_RES);
    for (int idx = lane; idx < WIN * DF; idx += 64) {
        int j = idx / DF, d = idx % DF;
        w[wv][j][d] = boundary ? (j == 0 ? f[(size_t)l * DF + d] : 0.f)
                               : f[(size_t)(l - 4 + j) * DF + d];
    }
    __syncthreads();
    attn_layer_w(w[wv], o1[wv], s[wv], g1, b1, mm[wv], vvv[wv], lane);
    attn_layer_w(o1[wv], o2[wv], s[wv], g2, b2, mm[wv], vvv[wv], lane);
    for (int idx = lane; idx < WIN * DF; idx += 64) {
        int j = idx / DF, d = idx % DF;
        cat[(size_t)l * 756 + j * 108 + d] = w[wv][j][d];
        cat[(size_t)l * 756 + j * 108 + DF + d] = o2[wv][j][d];
    }
}

// ---------------- transpose + f32->bf16: dst[n][m], rows m>=M zero-padded ----------------
__global__ __launch_bounds__(256) void transpose_to_bf16(const float* __restrict__ src,
                                                         unsigned short* __restrict__ dst,
                                                         int M, int N, int Mpad) {
    __shared__ float tile[32][33];
    int m0 = blockIdx.x * 32, n0 = blockIdx.y * 32;
    int c = threadIdx.x % 32, r0 = threadIdx.x / 32;
    #pragma unroll
    for (int rr = 0; rr < 4; ++rr) {
        int r = r0 + rr * 8, m = m0 + r;
        tile[r][c] = (m < M) ? src[(size_t)m * N + n0 + c] : 0.f;
    }
    __syncthreads();
    #pragma unroll
    for (int rr = 0; rr < 4; ++rr) {
        int r = r0 + rr * 8;
        dst[(size_t)(n0 + r) * Mpad + m0 + c] = f2bf(tile[c][r]);
    }
}

// zero bf16 y1 pad rows 2000..2047
__global__ __launch_bounds__(256) void zero_pad_rows(unsigned int* __restrict__ p) {
    int i = blockIdx.x * 256 + threadIdx.x;
    if (i < 196608) p[i] = 0u;
}

// ---------------- conv+pool -> Apool[nres*32][1024] bf16 (chunk-local rows) ----------------
__global__ __launch_bounds__(256) void conv_pool(
        const float* __restrict__ cat,
        const float* __restrict__ c1w, const float* __restrict__ c1b,
        const float* __restrict__ pa_p,
        const float* __restrict__ c2w, const float* __restrict__ c2b,
        const float* __restrict__ c3w, const float* __restrict__ c3b,
        unsigned short* __restrict__ Ap, int lbase) {
    int l = lbase + blockIdx.x;
    int t = threadIdx.x;
    __shared__ float catl[756];
    for (int i = t; i < 756; i += 256) catl[i] = cat[(size_t)l * 756 + i];
    __syncthreads();
    float pa = pa_p[0];
    size_t rowbase = (size_t)blockIdx.x * 32;
    for (int idx = t; idx < 3456; idx += 256) {
        int c = idx / 108, d = idx - c * 108;
        unsigned short* Arow = Ap + (rowbase + c) * 1024;
        float col[WIN];
        #pragma unroll
        for (int h = 0; h < WIN; ++h) col[h] = catl[h * 108 + d];
        {
            float w0 = c1w[c * 3], w1 = c1w[c * 3 + 1], w2 = c1w[c * 3 + 2], bb = c1b[c];
            float v[WIN];
            #pragma unroll
            for (int h = 0; h < WIN; ++h) {
                float sum = bb;
                if (h >= 1) sum = fmaf(w0, col[h - 1], sum);
                sum = fmaf(w1, col[h], sum);
                if (h <= 5) sum = fmaf(w2, col[h + 1], sum);
                v[h] = sum >= 0.f ? sum : pa * sum;
            }
            #pragma unroll
            for (int p = 0; p < 5; ++p)
                Arow[p * 108 + d] = f2bf(fmaxf(fmaxf(v[p], v[p + 1]), v[p + 2]));
        }
        {
            float wg[5], bb = c2b[c];
            #pragma unroll
            for (int x = 0; x < 5; ++x) wg[x] = c2w[c * 5 + x];
            float v[WIN];
            #pragma unroll
            for (int h = 0; h < WIN; ++h) {
                float sum = bb;
                #pragma unroll
                for (int x = 0; x < 5; ++x) {
                    int hh = h + x - 2;
                    if (hh >= 0 && hh <= 6) sum = fmaf(wg[x], col[hh], sum);
                }
                v[h] = fmaxf(sum, 0.f);
            }
            #pragma unroll
            for (int p = 0; p < 3; ++p) {
                float mx = v[p];
                #pragma unroll
                for (int r = 1; r < 5; ++r) mx = fmaxf(mx, v[p + r]);
                Arow[540 + p * 108 + d] = f2bf(mx);
            }
        }
        {
            float wg[7], bb = c3b[c];
            #pragma unroll
            for (int x = 0; x < 7; ++x) wg[x] = c3w[c * 7 + x];
            float mx = 0.f;
            #pragma unroll
            for (int h = 0; h < WIN; ++h) {
                float sum = bb;
                #pragma unroll
                for (int x = 0; x < 7; ++x) {
                    int hh = h + x - 3;
                    if (hh >= 0 && hh <= 6) sum = fmaf(wg[x], col[hh], sum);
                }
                mx = fmaxf(mx, fmaxf(sum, 0.f));
            }
            Arow[864 + d] = f2bf(mx);
        }
    }
    for (int i = t; i < 832; i += 256) {
        int r = i / 26, q = i - r * 26;
        *(unsigned int*)&Ap[(rowbase + r) * 1024 + 972 + q * 2] = 0u;
    }
}

// ---------------- Tiled MFMA GEMM: C[128x128] per block, BK=64, XOR-swizzled LDS ----------------
template<bool EPI_BF16>
__global__ __launch_bounds__(256) void gemm_tile(
        const unsigned short* __restrict__ A, long lda,
        const unsigned short* __restrict__ B, long ldb,
        int nk, const float* __restrict__ bias,
        unsigned short* __restrict__ outB, float* __restrict__ outF,
        long outRowBase) {
    __shared__ unsigned short ldsA[128 * 64];
    __shared__ unsigned short ldsB[128 * 64];
    int t = threadIdx.x, w = t >> 6, lane = t & 63;
    int m0 = blockIdx.x * 128, n0 = blockIdx.y * 128;
    long koff = (long)blockIdx.z * (long)nk * 64;
    A += koff; B += koff;
    int wr = w >> 1, wc = w & 1;
    int arow = lane & 15, kgrp = lane >> 4;

    const unsigned short* aS[4]; const unsigned short* bS[4];
    int aD[4];
    #pragma unroll
    for (int j = 0; j < 4; ++j) {
        int s = j * 256 + t, r = s >> 3, c = s & 7;
        aS[j] = A + (size_t)(m0 + r) * lda + c * 8;
        bS[j] = B + (size_t)(n0 + r) * ldb + c * 8;
        aD[j] = r * 64 + ((c ^ (r & 7)) * 8);
    }
    f32x4 acc[4][4];
    #pragma unroll
    for (int mi = 0; mi < 4; ++mi)
        #pragma unroll
        for (int ni = 0; ni < 4; ++ni) acc[mi][ni] = (f32x4)(0.f);

    ushort8v va[4], vb[4];
    #pragma unroll
    for (int j = 0; j < 4; ++j) { va[j] = *(const ushort8v*)(aS[j]); vb[j] = *(const ushort8v*)(bS[j]); }

    for (int ks = 0; ks < nk; ++ks) {
        __syncthreads();
        #pragma unroll
        for (int j = 0; j < 4; ++j) {
            *(ushort8v*)&ldsA[aD[j]] = va[j];
            *(ushort8v*)&ldsB[aD[j]] = vb[j];
        }
        __syncthreads();
        if (ks + 1 < nk) {
            #pragma unroll
            for (int j = 0; j < 4; ++j) {
                va[j] = *(const ushort8v*)(aS[j] + (ks + 1) * 64);
                vb[j] = *(const ushort8v*)(bS[j] + (ks + 1) * 64);
            }
        }
        #pragma unroll
        for (int kk = 0; kk < 2; ++kk) {
            int chunk = kk * 4 + kgrp;
            bf16x8 af[4], bfr[4];
            #pragma unroll
            for (int mi = 0; mi < 4; ++mi) {
                int rl = wr * 64 + mi * 16 + arow;
                af[mi] = *(const bf16x8*)&ldsA[rl * 64 + ((chunk ^ (rl & 7)) * 8)];
            }
            #pragma unroll
            for (int ni = 0; ni < 4; ++ni) {
                int rl = wc * 64 + ni * 16 + arow;
                bfr[ni] = *(const bf16x8*)&ldsB[rl * 64 + ((chunk ^ (rl & 7)) * 8)];
            }
            #pragma unroll
            for (int mi = 0; mi < 4; ++mi)
                #pragma unroll
                for (int ni = 0; ni < 4; ++ni)
                    acc[mi][ni] = __builtin_amdgcn_mfma_f32_16x16x32_bf16(af[mi], bfr[ni], acc[mi][ni], 0, 0, 0);
        }
    }
    #pragma unroll
    for (int ni = 0; ni < 4; ++ni) {
        int n = n0 + wc * 64 + ni * 16 + arow;
        float bv = EPI_BF16 ? bias[n] : 0.f;
        #pragma unroll
        for (int mi = 0; mi < 4; ++mi)
            #pragma unroll
            for (int r = 0; r < 4; ++r) {
                long m = m0 + wr * 64 + mi * 16 + kgrp * 4 + r;
                if (EPI_BF16)
                    outB[(outRowBase + m) * 256 + n] = f2bf(acc[mi][ni][r] + bv);
                else
                    outF[((long)blockIdx.z * 2048 + m) * 256 + n] = acc[mi][ni][r];
            }
    }
}

// ---------------- reduce partials + bias + leaky ----------------
__global__ __launch_bounds__(256) void reduce2(const float* __restrict__ part,
                                               const float* __restrict__ b2v,
                                               float* __restrict__ out) {
    int l = blockIdx.x, n = threadIdx.x;
    float sum = b2v[n];
    #pragma unroll
    for (int s = 0; s < 4; ++s) sum += part[((size_t)s * 2048 + l) * 256 + n];
    out[(size_t)l * 256 + n] = sum >= 0.f ? sum : 0.01f * sum;
}

extern "C" void kernel_launch(void* const* d_in, const int* in_sizes, int n_in,
                              void* d_out, int out_size, void* d_ws, size_t ws_size,
                              hipStream_t stream) {
    const float* beft = (const float*)d_in[0];
    const float* Wb  = (const float*)d_in[4];
    const float* bb  = (const float*)d_in[5];
    const float* g1  = (const float*)d_in[6];
    const float* b1  = (const float*)d_in[7];
    const float* g2  = (const float*)d_in[8];
    const float* b2  = (const float*)d_in[9];
    const float* c1w = (const float*)d_in[10];
    const float* c1b = (const float*)d_in[11];
    const float* pa  = (const float*)d_in[12];
    const float* c2w = (const float*)d_in[13];
    const float* c2b = (const float*)d_in[14];
    const float* c3w = (const float*)d_in[15];
    const float* c3b = (const float*)d_in[16];
    const float* W1  = (const float*)d_in[17];
    const float* b1v = (const float*)d_in[18];
    const float* W2  = (const float*)d_in[19];
    const float* b2v = (const float*)d_in[20];
    float* out = (float*)d_out;
    char* ws = (char*)d_ws;

    // layout (overlays are temporally disjoint):
    float*          f    = (float*)(ws + 0);                   // 432,000 B [dead after attn]
    float*          cat  = (float*)(ws + 524288);              // 6,048,000 B [dead after conv]
    float*          part = (float*)(ws + 0);                   // 8,388,608 B [gemm2 phase]
    unsigned short* W1T  = (unsigned short*)(ws + 8388608);    // 524,288 B
    unsigned short* W2T  = (unsigned short*)(ws + 8912896);    // 4,194,304 B
    unsigned short* y1   = (unsigned short*)(ws + 13107200);   // 33,554,432 B
    unsigned short* A2   = (unsigned short*)(ws + 13107200);   // 12,582,912 B [bert phase, overlays y1]
    unsigned short* B2T  = (unsigned short*)(ws + 25690112);   // 393,216 B    [bert phase, within y1]
    unsigned short* Ap   = (unsigned short*)(ws + 46661632);   // adaptive chunk

    long avail = (long)ws_size - 46661632L;
    long tpc = avail / (128L * 1024L * 2L);
    if (tpc < 1) tpc = 1;
    if (tpc > 500) tpc = 500;

    split_beft<<<2048, 256, 0, stream>>>(beft, A2);
    b2t_build<<<768, 256, 0, stream>>>(Wb, B2T);
    bert_mfma<<<16, 256, 0, stream>>>(A2, B2T, bb, f);
    window_attn4<<<500, 256, 0, stream>>>(f, g1, b1, g2, b2, cat);
    transpose_to_bf16<<<dim3(32, 8), 256, 0, stream>>>(W1, W1T, 972, 256, 1024);
    transpose_to_bf16<<<dim3(256, 8), 256, 0, stream>>>(W2, W2T, 8192, 256, 8192);
    zero_pad_rows<<<768, 256, 0, stream>>>((unsigned int*)(y1 + (size_t)2000 * 8192));

    for (long t0 = 0; t0 < 500; t0 += tpc) {
        long nt = (500 - t0 < tpc) ? (500 - t0) : tpc;
        conv_pool<<<(int)(nt * 4), 256, 0, stream>>>(cat, c1w, c1b, pa, c2w, c2b,
                                                     c3w, c3b, Ap, (int)(t0 * 4));
        gemm_tile<true><<<dim3((int)nt, 2, 1), 256, 0, stream>>>(
            Ap, 1024, W1T, 1024, 16, b1v, y1, nullptr, t0 * 128);
    }
    gemm_tile<false><<<dim3(16, 2, 4), 256, 0, stream>>>(
        y1, 8192, W2T, 8192, 32, nullptr, nullptr, part, 0);
    reduce2<<<L_RES, 256, 0, stream>>>(part, b2v, out);
}

// Round 6
// 180.646 us; speedup vs baseline: 4.1635x; 1.0555x over previous
//
#include <hip/hip_runtime.h>

#define L_RES 2000
#define DF 54
#define WIN 7

typedef short bf16x8 __attribute__((ext_vector_type(8)));
typedef float f32x4 __attribute__((ext_vector_type(4)));
typedef unsigned short ushort8v __attribute__((ext_vector_type(8)));

__device__ __forceinline__ unsigned short f2bf(float f) {
    unsigned int u = __float_as_uint(f);
    unsigned int r = (u + 0x7FFFu + ((u >> 16) & 1u)) >> 16;
    return (unsigned short)r;
}
__device__ __forceinline__ float bf2f(unsigned short h) {
    return __uint_as_float(((unsigned int)h) << 16);
}

// ---------------- bert stage a: split beft into A2 = [hi | lo | hi], K=3072, 2048 rows ----------------
__global__ __launch_bounds__(256) void split_beft(const float* __restrict__ beft,
                                                  unsigned short* __restrict__ A2) {
    int l = blockIdx.x;
    int t = threadIdx.x;
    unsigned short* row = A2 + (size_t)l * 3072;
    for (int k = t; k < 1024; k += 256) {
        unsigned short hi = 0, lo = 0;
        if (l < L_RES) {
            float x = beft[(size_t)l * 1024 + k];
            hi = f2bf(x);
            lo = f2bf(x - bf2f(hi));
        }
        row[k] = hi;
        row[1024 + k] = lo;
        row[2048 + k] = hi;
    }
}

// ---------------- bert stage b: B2T[64][3072]: segs {hi,hi,lo} of Wb^T ----------------
__global__ __launch_bounds__(256) void b2t_build(const float* __restrict__ Wb,
                                                 unsigned short* __restrict__ B2T) {
    int idx = blockIdx.x * 256 + threadIdx.x;   // 64*3072 = 196608
    int n = idx / 3072, col = idx % 3072;
    int seg = col >> 10, k = col & 1023;
    unsigned short r = 0;
    if (n < DF) {
        float v = Wb[(size_t)k * DF + n];
        unsigned short hi = f2bf(v);
        r = (seg < 2) ? hi : f2bf(v - bf2f(hi));
    }
    B2T[idx] = r;
}

// ---------------- bert stage c: MFMA GEMM M=2048 N=64 K=3072 -> f fp32 ----------------
__global__ __launch_bounds__(256) void bert_mfma(const unsigned short* __restrict__ A2,
                                                 const unsigned short* __restrict__ B2T,
                                                 const float* __restrict__ bb,
                                                 float* __restrict__ f) {
    __shared__ unsigned short ldsA[128 * 64];
    __shared__ unsigned short ldsB[64 * 64];
    int t = threadIdx.x, w = t >> 6, lane = t & 63;
    int m0 = blockIdx.x * 128;
    int wr = w >> 1, wc = w & 1;
    int arow = lane & 15, kgrp = lane >> 4;

    const unsigned short* aS[4]; const unsigned short* bS[2];
    int aD[4], bD[2];
    #pragma unroll
    for (int j = 0; j < 4; ++j) {
        int s = j * 256 + t, r = s >> 3, c = s & 7;
        aS[j] = A2 + (size_t)(m0 + r) * 3072 + c * 8;
        aD[j] = r * 64 + ((c ^ (r & 7)) * 8);
    }
    #pragma unroll
    for (int j = 0; j < 2; ++j) {
        int s = j * 256 + t, r = s >> 3, c = s & 7;
        bS[j] = B2T + (size_t)r * 3072 + c * 8;
        bD[j] = r * 64 + ((c ^ (r & 7)) * 8);
    }
    f32x4 acc[4][2];
    #pragma unroll
    for (int mi = 0; mi < 4; ++mi)
        #pragma unroll
        for (int ni = 0; ni < 2; ++ni) acc[mi][ni] = (f32x4)(0.f);

    ushort8v va[4], vb[2];
    #pragma unroll
    for (int j = 0; j < 4; ++j) va[j] = *(const ushort8v*)(aS[j]);
    #pragma unroll
    for (int j = 0; j < 2; ++j) vb[j] = *(const ushort8v*)(bS[j]);

    for (int ks = 0; ks < 48; ++ks) {
        __syncthreads();
        #pragma unroll
        for (int j = 0; j < 4; ++j) *(ushort8v*)&ldsA[aD[j]] = va[j];
        #pragma unroll
        for (int j = 0; j < 2; ++j) *(ushort8v*)&ldsB[bD[j]] = vb[j];
        __syncthreads();
        if (ks + 1 < 48) {
            #pragma unroll
            for (int j = 0; j < 4; ++j) va[j] = *(const ushort8v*)(aS[j] + (ks + 1) * 64);
            #pragma unroll
            for (int j = 0; j < 2; ++j) vb[j] = *(const ushort8v*)(bS[j] + (ks + 1) * 64);
        }
        #pragma unroll
        for (int kk = 0; kk < 2; ++kk) {
            int chunk = kk * 4 + kgrp;
            bf16x8 af[4], bfr[2];
            #pragma unroll
            for (int mi = 0; mi < 4; ++mi) {
                int rl = wr * 64 + mi * 16 + arow;
                af[mi] = *(const bf16x8*)&ldsA[rl * 64 + ((chunk ^ (rl & 7)) * 8)];
            }
            #pragma unroll
            for (int ni = 0; ni < 2; ++ni) {
                int rl = wc * 32 + ni * 16 + arow;
                bfr[ni] = *(const bf16x8*)&ldsB[rl * 64 + ((chunk ^ (rl & 7)) * 8)];
            }
            #pragma unroll
            for (int mi = 0; mi < 4; ++mi)
                #pragma unroll
                for (int ni = 0; ni < 2; ++ni)
                    acc[mi][ni] = __builtin_amdgcn_mfma_f32_16x16x32_bf16(af[mi], bfr[ni], acc[mi][ni], 0, 0, 0);
        }
    }
    #pragma unroll
    for (int ni = 0; ni < 2; ++ni) {
        int n = wc * 32 + ni * 16 + arow;
        if (n < DF) {
            float bv = bb[n];
            #pragma unroll
            for (int mi = 0; mi < 4; ++mi)
                #pragma unroll
                for (int r = 0; r < 4; ++r) {
                    int m = m0 + wr * 64 + mi * 16 + kgrp * 4 + r;
                    if (m < L_RES) f[(size_t)m * DF + n] = acc[mi][ni][r] + bv;
                }
        }
    }
}

// ---------------- window gather + attn x2 + concat, 4 residues (1 wave each) ----------------
__device__ __forceinline__ void attn_layer_w(const float (*in)[DF], float (*out)[DF],
                                             float (*s)[WIN][WIN],
                                             const float* __restrict__ g,
                                             const float* __restrict__ b,
                                             float* mm, float* vv, int lane) {
    for (int idx = lane; idx < 3 * WIN * WIN; idx += 64) {
        int h = idx / 49, r = idx % 49, q = r / WIN, k = r % WIN;
        float sum = 0.f;
        #pragma unroll
        for (int d = 0; d < 18; ++d) sum = fmaf(in[q][h * 18 + d], in[k][h * 18 + d], sum);
        s[h][q][k] = sum;
    }
    __syncthreads();
    for (int idx = lane; idx < 3 * WIN; idx += 64) {
        int h = idx / WIN, q = idx % WIN;
        float mx = s[h][q][0];
        #pragma unroll
        for (int k = 1; k < WIN; ++k) mx = fmaxf(mx, s[h][q][k]);
        float e[WIN], sum = 0.f;
        #pragma unroll
        for (int k = 0; k < WIN; ++k) { e[k] = expf(s[h][q][k] - mx); sum += e[k]; }
        float inv = 1.f / sum;
        #pragma unroll
        for (int k = 0; k < WIN; ++k) s[h][q][k] = e[k] * inv;
    }
    __syncthreads();
    for (int idx = lane; idx < WIN * DF; idx += 64) {
        int q = idx / DF, c = idx % DF, h = c / 18;
        float sum = 0.f;
        #pragma unroll
        for (int k = 0; k < WIN; ++k) sum = fmaf(s[h][q][k], in[k][c], sum);
        out[q][c] = sum;
    }
    __syncthreads();
    for (int q = lane; q < WIN; q += 64) {
        float m = 0.f;
        for (int c = 0; c < DF; ++c) m += out[q][c];
        m *= (1.f / DF);
        float v = 0.f;
        for (int c = 0; c < DF; ++c) { float d0 = out[q][c] - m; v = fmaf(d0, d0, v); }
        v *= (1.f / DF);
        mm[q] = m; vv[q] = rsqrtf(v + 1e-5f);
    }
    __syncthreads();
    for (int idx = lane; idx < WIN * DF; idx += 64) {
        int q = idx / DF, c = idx % DF;
        out[q][c] = (out[q][c] - mm[q]) * vv[q] * g[c] + b[c];
    }
    __syncthreads();
}

__global__ __launch_bounds__(256) void window_attn4(const float* __restrict__ f,
                                                    const float* __restrict__ g1,
                                                    const float* __restrict__ b1,
                                                    const float* __restrict__ g2,
                                                    const float* __restrict__ b2,
                                                    float* __restrict__ cat) {
    int wv = threadIdx.x >> 6, lane = threadIdx.x & 63;
    int l = blockIdx.x * 4 + wv;
    __shared__ float w[4][WIN][DF], o1[4][WIN][DF], o2[4][WIN][DF];
    __shared__ float s[4][3][WIN][WIN];
    __shared__ float mm[4][WIN], vvv[4][WIN];
    bool boundary = (l <= WIN) || (l + WIN >= L_RES);
    for (int idx = lane; idx < WIN * DF; idx += 64) {
        int j = idx / DF, d = idx % DF;
        w[wv][j][d] = boundary ? (j == 0 ? f[(size_t)l * DF + d] : 0.f)
                               : f[(size_t)(l - 4 + j) * DF + d];
    }
    __syncthreads();
    attn_layer_w(w[wv], o1[wv], s[wv], g1, b1, mm[wv], vvv[wv], lane);
    attn_layer_w(o1[wv], o2[wv], s[wv], g2, b2, mm[wv], vvv[wv], lane);
    for (int idx = lane; idx < WIN * DF; idx += 64) {
        int j = idx / DF, d = idx % DF;
        cat[(size_t)l * 756 + j * 108 + d] = w[wv][j][d];
        cat[(size_t)l * 756 + j * 108 + DF + d] = o2[wv][j][d];
    }
}

// ---------------- transpose + f32->bf16: dst[n][m], rows m>=M zero-padded ----------------
__global__ __launch_bounds__(256) void transpose_to_bf16(const float* __restrict__ src,
                                                         unsigned short* __restrict__ dst,
                                                         int M, int N, int Mpad) {
    __shared__ float tile[32][33];
    int m0 = blockIdx.x * 32, n0 = blockIdx.y * 32;
    int c = threadIdx.x % 32, r0 = threadIdx.x / 32;
    #pragma unroll
    for (int rr = 0; rr < 4; ++rr) {
        int r = r0 + rr * 8, m = m0 + r;
        tile[r][c] = (m < M) ? src[(size_t)m * N + n0 + c] : 0.f;
    }
    __syncthreads();
    #pragma unroll
    for (int rr = 0; rr < 4; ++rr) {
        int r = r0 + rr * 8;
        dst[(size_t)(n0 + r) * Mpad + m0 + c] = f2bf(tile[c][r]);
    }
}

// zero bf16 y1 pad rows 2000..2047
__global__ __launch_bounds__(256) void zero_pad_rows(unsigned int* __restrict__ p) {
    int i = blockIdx.x * 256 + threadIdx.x;
    if (i < 196608) p[i] = 0u;
}

// ---------------- conv+pool -> Apool[nres*32][1024] bf16 (chunk-local rows) ----------------
__global__ __launch_bounds__(256) void conv_pool(
        const float* __restrict__ cat,
        const float* __restrict__ c1w, const float* __restrict__ c1b,
        const float* __restrict__ pa_p,
        const float* __restrict__ c2w, const float* __restrict__ c2b,
        const float* __restrict__ c3w, const float* __restrict__ c3b,
        unsigned short* __restrict__ Ap, int lbase) {
    int l = lbase + blockIdx.x;
    int t = threadIdx.x;
    __shared__ float catl[756];
    for (int i = t; i < 756; i += 256) catl[i] = cat[(size_t)l * 756 + i];
    __syncthreads();
    float pa = pa_p[0];
    size_t rowbase = (size_t)blockIdx.x * 32;
    for (int idx = t; idx < 3456; idx += 256) {
        int c = idx / 108, d = idx - c * 108;
        unsigned short* Arow = Ap + (rowbase + c) * 1024;
        float col[WIN];
        #pragma unroll
        for (int h = 0; h < WIN; ++h) col[h] = catl[h * 108 + d];
        {
            float w0 = c1w[c * 3], w1 = c1w[c * 3 + 1], w2 = c1w[c * 3 + 2], bb = c1b[c];
            float v[WIN];
            #pragma unroll
            for (int h = 0; h < WIN; ++h) {
                float sum = bb;
                if (h >= 1) sum = fmaf(w0, col[h - 1], sum);
                sum = fmaf(w1, col[h], sum);
                if (h <= 5) sum = fmaf(w2, col[h + 1], sum);
                v[h] = sum >= 0.f ? sum : pa * sum;
            }
            #pragma unroll
            for (int p = 0; p < 5; ++p)
                Arow[p * 108 + d] = f2bf(fmaxf(fmaxf(v[p], v[p + 1]), v[p + 2]));
        }
        {
            float wg[5], bb = c2b[c];
            #pragma unroll
            for (int x = 0; x < 5; ++x) wg[x] = c2w[c * 5 + x];
            float v[WIN];
            #pragma unroll
            for (int h = 0; h < WIN; ++h) {
                float sum = bb;
                #pragma unroll
                for (int x = 0; x < 5; ++x) {
                    int hh = h + x - 2;
                    if (hh >= 0 && hh <= 6) sum = fmaf(wg[x], col[hh], sum);
                }
                v[h] = fmaxf(sum, 0.f);
            }
            #pragma unroll
            for (int p = 0; p < 3; ++p) {
                float mx = v[p];
                #pragma unroll
                for (int r = 1; r < 5; ++r) mx = fmaxf(mx, v[p + r]);
                Arow[540 + p * 108 + d] = f2bf(mx);
            }
        }
        {
            float wg[7], bb = c3b[c];
            #pragma unroll
            for (int x = 0; x < 7; ++x) wg[x] = c3w[c * 7 + x];
            float mx = 0.f;
            #pragma unroll
            for (int h = 0; h < WIN; ++h) {
                float sum = bb;
                #pragma unroll
                for (int x = 0; x < 7; ++x) {
                    int hh = h + x - 3;
                    if (hh >= 0 && hh <= 6) sum = fmaf(wg[x], col[hh], sum);
                }
                mx = fmaxf(mx, fmaxf(sum, 0.f));
            }
            Arow[864 + d] = f2bf(mx);
        }
    }
    for (int i = t; i < 832; i += 256) {
        int r = i / 26, q = i - r * 26;
        *(unsigned int*)&Ap[(rowbase + r) * 1024 + 972 + q * 2] = 0u;
    }
}

// ---------------- 8-wave tiled MFMA GEMM: C[128x256] per block, BK=64, XOR-swizzled LDS ----------------
// grid.x flat; z = bid & (2^ZBITS-1) selects K-slice (nk*64 each), m-tile = bid >> ZBITS.
// With ZBITS=3 consecutive blocks round-robin XCDs -> all m-tiles of one z share an XCD L2 for B.
template<bool EPI_BF16, int ZBITS>
__global__ __launch_bounds__(512) void gemm_tile8(
        const unsigned short* __restrict__ A, long lda,
        const unsigned short* __restrict__ B, long ldb,
        int nk, const float* __restrict__ bias,
        unsigned short* __restrict__ outB, float* __restrict__ outF,
        long outRowBase) {
    __shared__ unsigned short ldsA[128 * 64];
    __shared__ unsigned short ldsB[256 * 64];
    int t = threadIdx.x, w = t >> 6, lane = t & 63;
    int bid = blockIdx.x;
    int z = bid & ((1 << ZBITS) - 1);
    long m0 = (long)(bid >> ZBITS) * 128;
    long koff = (long)z * (long)nk * 64;
    A += koff; B += koff;
    int wr = w >> 2, wc = w & 3;                 // 2 x 4 wave grid, 64x64 each
    int arow = lane & 15, kgrp = lane >> 4;

    const unsigned short* aS[2]; const unsigned short* bS[4];
    int aD[2], bD[4];
    #pragma unroll
    for (int j = 0; j < 2; ++j) {
        int s = j * 512 + t, r = s >> 3, c = s & 7;
        aS[j] = A + (size_t)(m0 + r) * lda + c * 8;
        aD[j] = r * 64 + ((c ^ (r & 7)) * 8);
    }
    #pragma unroll
    for (int j = 0; j < 4; ++j) {
        int s = j * 512 + t, r = s >> 3, c = s & 7;
        bS[j] = B + (size_t)r * ldb + c * 8;
        bD[j] = r * 64 + ((c ^ (r & 7)) * 8);
    }
    f32x4 acc[4][4];
    #pragma unroll
    for (int mi = 0; mi < 4; ++mi)
        #pragma unroll
        for (int ni = 0; ni < 4; ++ni) acc[mi][ni] = (f32x4)(0.f);

    ushort8v va[2], vb[4];
    #pragma unroll
    for (int j = 0; j < 2; ++j) va[j] = *(const ushort8v*)(aS[j]);
    #pragma unroll
    for (int j = 0; j < 4; ++j) vb[j] = *(const ushort8v*)(bS[j]);

    for (int ks = 0; ks < nk; ++ks) {
        __syncthreads();
        #pragma unroll
        for (int j = 0; j < 2; ++j) *(ushort8v*)&ldsA[aD[j]] = va[j];
        #pragma unroll
        for (int j = 0; j < 4; ++j) *(ushort8v*)&ldsB[bD[j]] = vb[j];
        __syncthreads();
        if (ks + 1 < nk) {
            #pragma unroll
            for (int j = 0; j < 2; ++j) va[j] = *(const ushort8v*)(aS[j] + (ks + 1) * 64);
            #pragma unroll
            for (int j = 0; j < 4; ++j) vb[j] = *(const ushort8v*)(bS[j] + (ks + 1) * 64);
        }
        #pragma unroll
        for (int kk = 0; kk < 2; ++kk) {
            int chunk = kk * 4 + kgrp;
            bf16x8 af[4], bfr[4];
            #pragma unroll
            for (int mi = 0; mi < 4; ++mi) {
                int rl = wr * 64 + mi * 16 + arow;
                af[mi] = *(const bf16x8*)&ldsA[rl * 64 + ((chunk ^ (rl & 7)) * 8)];
            }
            #pragma unroll
            for (int ni = 0; ni < 4; ++ni) {
                int rl = wc * 64 + ni * 16 + arow;
                bfr[ni] = *(const bf16x8*)&ldsB[rl * 64 + ((chunk ^ (rl & 7)) * 8)];
            }
            #pragma unroll
            for (int mi = 0; mi < 4; ++mi)
                #pragma unroll
                for (int ni = 0; ni < 4; ++ni)
                    acc[mi][ni] = __builtin_amdgcn_mfma_f32_16x16x32_bf16(af[mi], bfr[ni], acc[mi][ni], 0, 0, 0);
        }
    }
    #pragma unroll
    for (int ni = 0; ni < 4; ++ni) {
        int n = wc * 64 + ni * 16 + arow;
        float bv = EPI_BF16 ? bias[n] : 0.f;
        #pragma unroll
        for (int mi = 0; mi < 4; ++mi)
            #pragma unroll
            for (int r = 0; r < 4; ++r) {
                long m = m0 + wr * 64 + mi * 16 + kgrp * 4 + r;
                if (EPI_BF16)
                    outB[(outRowBase + m) * 256 + n] = f2bf(acc[mi][ni][r] + bv);
                else
                    outF[((long)z * 2048 + m) * 256 + n] = acc[mi][ni][r];
            }
    }
}

// ---------------- reduce partials + bias + leaky ----------------
__global__ __launch_bounds__(256) void reduce2(const float* __restrict__ part,
                                               const float* __restrict__ b2v,
                                               float* __restrict__ out) {
    int l = blockIdx.x, n = threadIdx.x;
    float sum = b2v[n];
    #pragma unroll
    for (int s = 0; s < 8; ++s) sum += part[((size_t)s * 2048 + l) * 256 + n];
    out[(size_t)l * 256 + n] = sum >= 0.f ? sum : 0.01f * sum;
}

extern "C" void kernel_launch(void* const* d_in, const int* in_sizes, int n_in,
                              void* d_out, int out_size, void* d_ws, size_t ws_size,
                              hipStream_t stream) {
    const float* beft = (const float*)d_in[0];
    const float* Wb  = (const float*)d_in[4];
    const float* bb  = (const float*)d_in[5];
    const float* g1  = (const float*)d_in[6];
    const float* b1  = (const float*)d_in[7];
    const float* g2  = (const float*)d_in[8];
    const float* b2  = (const float*)d_in[9];
    const float* c1w = (const float*)d_in[10];
    const float* c1b = (const float*)d_in[11];
    const float* pa  = (const float*)d_in[12];
    const float* c2w = (const float*)d_in[13];
    const float* c2b = (const float*)d_in[14];
    const float* c3w = (const float*)d_in[15];
    const float* c3b = (const float*)d_in[16];
    const float* W1  = (const float*)d_in[17];
    const float* b1v = (const float*)d_in[18];
    const float* W2  = (const float*)d_in[19];
    const float* b2v = (const float*)d_in[20];
    float* out = (float*)d_out;
    char* ws = (char*)d_ws;

    // layout (overlays are temporally disjoint):
    float*          f    = (float*)(ws + 0);                   // 432,000 B [dead after attn]
    float*          cat  = (float*)(ws + 524288);              // 6,048,000 B [dead after conv]
    unsigned short* W1T  = (unsigned short*)(ws + 8388608);    // 524,288 B
    unsigned short* W2T  = (unsigned short*)(ws + 8912896);    // 4,194,304 B
    unsigned short* y1   = (unsigned short*)(ws + 13107200);   // 33,554,432 B
    unsigned short* A2   = (unsigned short*)(ws + 13107200);   // 12,582,912 B [bert phase, overlays y1]
    unsigned short* B2T  = (unsigned short*)(ws + 25690112);   // 393,216 B    [bert phase, within y1]
    unsigned short* Ap   = (unsigned short*)(ws + 46661632);   // Apool chunk [dead after gemm1]
    float*          part = (float*)(ws + 46661632);            // 16,777,216 B [gemm2 phase, overlays Ap]

    long avail = (long)ws_size - 46661632L;
    long tpc = avail / (128L * 1024L * 2L);
    if (tpc < 1) tpc = 1;
    if (tpc > 500) tpc = 500;

    split_beft<<<2048, 256, 0, stream>>>(beft, A2);
    b2t_build<<<768, 256, 0, stream>>>(Wb, B2T);
    bert_mfma<<<16, 256, 0, stream>>>(A2, B2T, bb, f);
    window_attn4<<<500, 256, 0, stream>>>(f, g1, b1, g2, b2, cat);
    transpose_to_bf16<<<dim3(32, 8), 256, 0, stream>>>(W1, W1T, 972, 256, 1024);
    transpose_to_bf16<<<dim3(256, 8), 256, 0, stream>>>(W2, W2T, 8192, 256, 8192);
    zero_pad_rows<<<768, 256, 0, stream>>>((unsigned int*)(y1 + (size_t)2000 * 8192));

    for (long t0 = 0; t0 < 500; t0 += tpc) {
        long nt = (500 - t0 < tpc) ? (500 - t0) : tpc;
        conv_pool<<<(int)(nt * 4), 256, 0, stream>>>(cat, c1w, c1b, pa, c2w, c2b,
                                                     c3w, c3b, Ap, (int)(t0 * 4));
        gemm_tile8<true, 0><<<(int)nt, 512, 0, stream>>>(
            Ap, 1024, W1T, 1024, 16, b1v, y1, nullptr, t0 * 128);
    }
    gemm_tile8<false, 3><<<128, 512, 0, stream>>>(
        y1, 8192, W2T, 8192, 16, nullptr, nullptr, part, 0);
    reduce2<<<L_RES, 256, 0, stream>>>(part, b2v, out);
}

// Round 7
// 169.357 us; speedup vs baseline: 4.4410x; 1.0667x over previous
//
#include <hip/hip_runtime.h>

#define L_RES 2000
#define DF 54
#define WIN 7

typedef short bf16x8 __attribute__((ext_vector_type(8)));
typedef float f32x4 __attribute__((ext_vector_type(4)));
typedef unsigned short ushort8v __attribute__((ext_vector_type(8)));

__device__ __forceinline__ unsigned short f2bf(float f) {
    unsigned int u = __float_as_uint(f);
    unsigned int r = (u + 0x7FFFu + ((u >> 16) & 1u)) >> 16;
    return (unsigned short)r;
}
__device__ __forceinline__ float bf2f(unsigned short h) {
    return __uint_as_float(((unsigned int)h) << 16);
}
// async global->LDS, 16B per lane; LDS dest = wave-uniform base + lane*16
__device__ __forceinline__ void gload16(const unsigned short* g, unsigned short* l) {
    __builtin_amdgcn_global_load_lds(
        (const __attribute__((address_space(1))) void*)g,
        (__attribute__((address_space(3))) void*)l, 16, 0, 0);
}

// ---------------- bert stage a: split beft into A2 = [hi | lo | hi], K=3072, 2048 rows ----------------
__global__ __launch_bounds__(256) void split_beft(const float* __restrict__ beft,
                                                  unsigned short* __restrict__ A2) {
    int l = blockIdx.x;
    int t = threadIdx.x;
    unsigned short* row = A2 + (size_t)l * 3072;
    for (int k = t; k < 1024; k += 256) {
        unsigned short hi = 0, lo = 0;
        if (l < L_RES) {
            float x = beft[(size_t)l * 1024 + k];
            hi = f2bf(x);
            lo = f2bf(x - bf2f(hi));
        }
        row[k] = hi;
        row[1024 + k] = lo;
        row[2048 + k] = hi;
    }
}

// ---------------- bert stage b: B2T[64][3072]: segs {hi,hi,lo} of Wb^T ----------------
__global__ __launch_bounds__(256) void b2t_build(const float* __restrict__ Wb,
                                                 unsigned short* __restrict__ B2T) {
    int idx = blockIdx.x * 256 + threadIdx.x;   // 64*3072 = 196608
    int n = idx / 3072, col = idx % 3072;
    int seg = col >> 10, k = col & 1023;
    unsigned short r = 0;
    if (n < DF) {
        float v = Wb[(size_t)k * DF + n];
        unsigned short hi = f2bf(v);
        r = (seg < 2) ? hi : f2bf(v - bf2f(hi));
    }
    B2T[idx] = r;
}

// ---------------- bert stage c: MFMA GEMM M=2048 N=64, K-split z=4 -> fp32 partials ----------------
__global__ __launch_bounds__(256) void bert_mfma(const unsigned short* __restrict__ A2,
                                                 const unsigned short* __restrict__ B2T,
                                                 float* __restrict__ bpart) {
    __shared__ unsigned short ldsA[128 * 64];
    __shared__ unsigned short ldsB[64 * 64];
    int t = threadIdx.x, w = t >> 6, lane = t & 63;
    int m0 = blockIdx.x * 128;
    int z = blockIdx.y;                       // 4 K-slices of 768
    long koff = (long)z * 768;
    int wr = w >> 1, wc = w & 1;
    int arow = lane & 15, kgrp = lane >> 4;

    const unsigned short* aS[4]; const unsigned short* bS[2];
    int aD[4], bD[2];
    #pragma unroll
    for (int j = 0; j < 4; ++j) {
        int s = j * 256 + t, r = s >> 3, c = s & 7;
        aS[j] = A2 + koff + (size_t)(m0 + r) * 3072 + c * 8;
        aD[j] = r * 64 + ((c ^ (r & 7)) * 8);
    }
    #pragma unroll
    for (int j = 0; j < 2; ++j) {
        int s = j * 256 + t, r = s >> 3, c = s & 7;
        bS[j] = B2T + koff + (size_t)r * 3072 + c * 8;
        bD[j] = r * 64 + ((c ^ (r & 7)) * 8);
    }
    f32x4 acc[4][2];
    #pragma unroll
    for (int mi = 0; mi < 4; ++mi)
        #pragma unroll
        for (int ni = 0; ni < 2; ++ni) acc[mi][ni] = (f32x4)(0.f);

    ushort8v va[4], vb[2];
    #pragma unroll
    for (int j = 0; j < 4; ++j) va[j] = *(const ushort8v*)(aS[j]);
    #pragma unroll
    for (int j = 0; j < 2; ++j) vb[j] = *(const ushort8v*)(bS[j]);

    for (int ks = 0; ks < 12; ++ks) {
        __syncthreads();
        #pragma unroll
        for (int j = 0; j < 4; ++j) *(ushort8v*)&ldsA[aD[j]] = va[j];
        #pragma unroll
        for (int j = 0; j < 2; ++j) *(ushort8v*)&ldsB[bD[j]] = vb[j];
        __syncthreads();
        if (ks + 1 < 12) {
            #pragma unroll
            for (int j = 0; j < 4; ++j) va[j] = *(const ushort8v*)(aS[j] + (ks + 1) * 64);
            #pragma unroll
            for (int j = 0; j < 2; ++j) vb[j] = *(const ushort8v*)(bS[j] + (ks + 1) * 64);
        }
        #pragma unroll
        for (int kk = 0; kk < 2; ++kk) {
            int chunk = kk * 4 + kgrp;
            bf16x8 af[4], bfr[2];
            #pragma unroll
            for (int mi = 0; mi < 4; ++mi) {
                int rl = wr * 64 + mi * 16 + arow;
                af[mi] = *(const bf16x8*)&ldsA[rl * 64 + ((chunk ^ (rl & 7)) * 8)];
            }
            #pragma unroll
            for (int ni = 0; ni < 2; ++ni) {
                int rl = wc * 32 + ni * 16 + arow;
                bfr[ni] = *(const bf16x8*)&ldsB[rl * 64 + ((chunk ^ (rl & 7)) * 8)];
            }
            #pragma unroll
            for (int mi = 0; mi < 4; ++mi)
                #pragma unroll
                for (int ni = 0; ni < 2; ++ni)
                    acc[mi][ni] = __builtin_amdgcn_mfma_f32_16x16x32_bf16(af[mi], bfr[ni], acc[mi][ni], 0, 0, 0);
        }
    }
    #pragma unroll
    for (int ni = 0; ni < 2; ++ni) {
        int n = wc * 32 + ni * 16 + arow;
        #pragma unroll
        for (int mi = 0; mi < 4; ++mi)
            #pragma unroll
            for (int r = 0; r < 4; ++r) {
                int m = m0 + wr * 64 + mi * 16 + kgrp * 4 + r;
                bpart[((size_t)z * 2048 + m) * 64 + n] = acc[mi][ni][r];
            }
    }
}

// ---------------- bert stage d: reduce 4 partials + bias -> f (L,54) ----------------
__global__ __launch_bounds__(64) void bert_reduce(const float* __restrict__ bpart,
                                                  const float* __restrict__ bb,
                                                  float* __restrict__ f) {
    int l = blockIdx.x, n = threadIdx.x;
    if (n < DF) {
        float s = bb[n];
        #pragma unroll
        for (int z = 0; z < 4; ++z) s += bpart[((size_t)z * 2048 + l) * 64 + n];
        f[(size_t)l * DF + n] = s;
    }
}

// ---------------- window gather + attn x2 + concat, 4 residues (1 wave each) ----------------
__device__ __forceinline__ void attn_layer_w(const float (*in)[DF], float (*out)[DF],
                                             float (*s)[WIN][WIN],
                                             const float* __restrict__ g,
                                             const float* __restrict__ b,
                                             float* mm, float* vv, int lane) {
    for (int idx = lane; idx < 3 * WIN * WIN; idx += 64) {
        int h = idx / 49, r = idx % 49, q = r / WIN, k = r % WIN;
        float sum = 0.f;
        #pragma unroll
        for (int d = 0; d < 18; ++d) sum = fmaf(in[q][h * 18 + d], in[k][h * 18 + d], sum);
        s[h][q][k] = sum;
    }
    __syncthreads();
    for (int idx = lane; idx < 3 * WIN; idx += 64) {
        int h = idx / WIN, q = idx % WIN;
        float mx = s[h][q][0];
        #pragma unroll
        for (int k = 1; k < WIN; ++k) mx = fmaxf(mx, s[h][q][k]);
        float e[WIN], sum = 0.f;
        #pragma unroll
        for (int k = 0; k < WIN; ++k) { e[k] = expf(s[h][q][k] - mx); sum += e[k]; }
        float inv = 1.f / sum;
        #pragma unroll
        for (int k = 0; k < WIN; ++k) s[h][q][k] = e[k] * inv;
    }
    __syncthreads();
    for (int idx = lane; idx < WIN * DF; idx += 64) {
        int q = idx / DF, c = idx % DF, h = c / 18;
        float sum = 0.f;
        #pragma unroll
        for (int k = 0; k < WIN; ++k) sum = fmaf(s[h][q][k], in[k][c], sum);
        out[q][c] = sum;
    }
    __syncthreads();
    for (int q = lane; q < WIN; q += 64) {
        float m = 0.f;
        for (int c = 0; c < DF; ++c) m += out[q][c];
        m *= (1.f / DF);
        float v = 0.f;
        for (int c = 0; c < DF; ++c) { float d0 = out[q][c] - m; v = fmaf(d0, d0, v); }
        v *= (1.f / DF);
        mm[q] = m; vv[q] = rsqrtf(v + 1e-5f);
    }
    __syncthreads();
    for (int idx = lane; idx < WIN * DF; idx += 64) {
        int q = idx / DF, c = idx % DF;
        out[q][c] = (out[q][c] - mm[q]) * vv[q] * g[c] + b[c];
    }
    __syncthreads();
}

__global__ __launch_bounds__(256) void window_attn4(const float* __restrict__ f,
                                                    const float* __restrict__ g1,
                                                    const float* __restrict__ b1,
                                                    const float* __restrict__ g2,
                                                    const float* __restrict__ b2,
                                                    float* __restrict__ cat) {
    int wv = threadIdx.x >> 6, lane = threadIdx.x & 63;
    int l = blockIdx.x * 4 + wv;
    __shared__ float w[4][WIN][DF], o1[4][WIN][DF], o2[4][WIN][DF];
    __shared__ float s[4][3][WIN][WIN];
    __shared__ float mm[4][WIN], vvv[4][WIN];
    bool boundary = (l <= WIN) || (l + WIN >= L_RES);
    for (int idx = lane; idx < WIN * DF; idx += 64) {
        int j = idx / DF, d = idx % DF;
        w[wv][j][d] = boundary ? (j == 0 ? f[(size_t)l * DF + d] : 0.f)
                               : f[(size_t)(l - 4 + j) * DF + d];
    }
    __syncthreads();
    attn_layer_w(w[wv], o1[wv], s[wv], g1, b1, mm[wv], vvv[wv], lane);
    attn_layer_w(o1[wv], o2[wv], s[wv], g2, b2, mm[wv], vvv[wv], lane);
    for (int idx = lane; idx < WIN * DF; idx += 64) {
        int j = idx / DF, d = idx % DF;
        cat[(size_t)l * 756 + j * 108 + d] = w[wv][j][d];
        cat[(size_t)l * 756 + j * 108 + DF + d] = o2[wv][j][d];
    }
}

// ---------------- transpose + f32->bf16: dst[n][m], rows m>=M zero-padded ----------------
__global__ __launch_bounds__(256) void transpose_to_bf16(const float* __restrict__ src,
                                                         unsigned short* __restrict__ dst,
                                                         int M, int N, int Mpad) {
    __shared__ float tile[32][33];
    int m0 = blockIdx.x * 32, n0 = blockIdx.y * 32;
    int c = threadIdx.x % 32, r0 = threadIdx.x / 32;
    #pragma unroll
    for (int rr = 0; rr < 4; ++rr) {
        int r = r0 + rr * 8, m = m0 + r;
        tile[r][c] = (m < M) ? src[(size_t)m * N + n0 + c] : 0.f;
    }
    __syncthreads();
    #pragma unroll
    for (int rr = 0; rr < 4; ++rr) {
        int r = r0 + rr * 8;
        dst[(size_t)(n0 + r) * Mpad + m0 + c] = f2bf(tile[c][r]);
    }
}

// zero bf16 y1 pad rows 2000..2047
__global__ __launch_bounds__(256) void zero_pad_rows(unsigned int* __restrict__ p) {
    int i = blockIdx.x * 256 + threadIdx.x;
    if (i < 196608) p[i] = 0u;
}

// ---------------- conv+pool -> Apool[nres*32][1024] bf16, LDS-staged + coalesced store ----------------
__global__ __launch_bounds__(256) void conv_pool(
        const float* __restrict__ cat,
        const float* __restrict__ c1w, const float* __restrict__ c1b,
        const float* __restrict__ pa_p,
        const float* __restrict__ c2w, const float* __restrict__ c2b,
        const float* __restrict__ c3w, const float* __restrict__ c3b,
        unsigned short* __restrict__ Ap, int lbase) {
    int l = lbase + blockIdx.x;
    int t = threadIdx.x;
    __shared__ float catl[756];
    __shared__ unsigned short Al[32 * 1024];   // 64 KB staging
    for (int i = t; i < 756; i += 256) catl[i] = cat[(size_t)l * 756 + i];
    // zero K-pad cols 972..1023 in LDS
    for (int i = t; i < 832; i += 256) {
        int r = i / 26, q = i - r * 26;
        *(unsigned int*)&Al[r * 1024 + 972 + q * 2] = 0u;
    }
    __syncthreads();
    float pa = pa_p[0];
    for (int idx = t; idx < 3456; idx += 256) {
        int c = idx / 108, d = idx - c * 108;
        unsigned short* Arow = Al + c * 1024;
        float col[WIN];
        #pragma unroll
        for (int h = 0; h < WIN; ++h) col[h] = catl[h * 108 + d];
        {   // branch 1: k=3, prelu, pool3 -> 5 outputs
            float w0 = c1w[c * 3], w1 = c1w[c * 3 + 1], w2 = c1w[c * 3 + 2], bb = c1b[c];
            float v[WIN];
            #pragma unroll
            for (int h = 0; h < WIN; ++h) {
                float sum = bb;
                if (h >= 1) sum = fmaf(w0, col[h - 1], sum);
                sum = fmaf(w1, col[h], sum);
                if (h <= 5) sum = fmaf(w2, col[h + 1], sum);
                v[h] = sum >= 0.f ? sum : pa * sum;
            }
            #pragma unroll
            for (int p = 0; p < 5; ++p)
                Arow[p * 108 + d] = f2bf(fmaxf(fmaxf(v[p], v[p + 1]), v[p + 2]));
        }
        {   // branch 2: k=5, relu, pool5 -> 3 outputs
            float wg[5], bb = c2b[c];
            #pragma unroll
            for (int x = 0; x < 5; ++x) wg[x] = c2w[c * 5 + x];
            float v[WIN];
            #pragma unroll
            for (int h = 0; h < WIN; ++h) {
                float sum = bb;
                #pragma unroll
                for (int x = 0; x < 5; ++x) {
                    int hh = h + x - 2;
                    if (hh >= 0 && hh <= 6) sum = fmaf(wg[x], col[hh], sum);
                }
                v[h] = fmaxf(sum, 0.f);
            }
            #pragma unroll
            for (int p = 0; p < 3; ++p) {
                float mx = v[p];
                #pragma unroll
                for (int r = 1; r < 5; ++r) mx = fmaxf(mx, v[p + r]);
                Arow[540 + p * 108 + d] = f2bf(mx);
            }
        }
        {   // branch 3: k=7, relu, pool7 -> 1 output
            float wg[7], bb = c3b[c];
            #pragma unroll
            for (int x = 0; x < 7; ++x) wg[x] = c3w[c * 7 + x];
            float mx = 0.f;
            #pragma unroll
            for (int h = 0; h < WIN; ++h) {
                float sum = bb;
                #pragma unroll
                for (int x = 0; x < 7; ++x) {
                    int hh = h + x - 3;
                    if (hh >= 0 && hh <= 6) sum = fmaf(wg[x], col[hh], sum);
                }
                mx = fmaxf(mx, fmaxf(sum, 0.f));
            }
            Arow[864 + d] = f2bf(mx);
        }
    }
    __syncthreads();
    // coalesced 16B copy LDS -> global
    unsigned short* dst = Ap + (size_t)blockIdx.x * 32768;
    #pragma unroll
    for (int i = 0; i < 16; ++i) {
        int e = (i * 256 + t) * 8;
        *(ushort8v*)&dst[e] = *(const ushort8v*)&Al[e];
    }
}

// ---------------- 8-wave tiled MFMA GEMM, global_load_lds staging, C[128x256]/block ----------------
// LDS kept LINEAR; the XOR swizzle is applied to the per-lane GLOBAL source column (c^ra,
// an involution) so swizzled ds_read_b128 finds source[r][chunk] at col chunk^(r&7).
template<bool EPI_BF16, int ZBITS>
__global__ __launch_bounds__(512) void gemm_tile8(
        const unsigned short* __restrict__ A, long lda,
        const unsigned short* __restrict__ B, long ldb,
        int nk, const float* __restrict__ bias,
        unsigned short* __restrict__ outB, float* __restrict__ outF,
        long outRowBase) {
    __shared__ unsigned short ldsA[128 * 64];
    __shared__ unsigned short ldsB[256 * 64];
    int t = threadIdx.x, w = t >> 6, lane = t & 63;
    int bid = blockIdx.x;
    int z = bid & ((1 << ZBITS) - 1);
    long m0 = (long)(bid >> ZBITS) * 128;
    long koff = (long)z * (long)nk * 64;
    A += koff; B += koff;
    int wr = w >> 2, wc = w & 3;                 // 2 x 4 wave grid, 64x64 each
    int arow = lane & 15, kgrp = lane >> 4;
    int ra = lane >> 3, cc = lane & 7;
    int csw = (cc ^ ra) * 8;                     // pre-swizzled source column

    const unsigned short* gA[2]; const unsigned short* gB[4];
    unsigned short* dA[2]; unsigned short* dB[4];
    #pragma unroll
    for (int j = 0; j < 2; ++j) {
        int rbase = j * 64 + w * 8;
        gA[j] = A + (size_t)(m0 + rbase + ra) * lda + csw;
        dA[j] = &ldsA[rbase * 64];
    }
    #pragma unroll
    for (int j = 0; j < 4; ++j) {
        int rbase = j * 64 + w * 8;
        gB[j] = B + (size_t)(rbase + ra) * ldb + csw;
        dB[j] = &ldsB[rbase * 64];
    }
    f32x4 acc[4][4];
    #pragma unroll
    for (int mi = 0; mi < 4; ++mi)
        #pragma unroll
        for (int ni = 0; ni < 4; ++ni) acc[mi][ni] = (f32x4)(0.f);

    for (int ks = 0; ks < nk; ++ks) {
        #pragma unroll
        for (int j = 0; j < 2; ++j) gload16(gA[j] + ks * 64, dA[j]);
        #pragma unroll
        for (int j = 0; j < 4; ++j) gload16(gB[j] + ks * 64, dB[j]);
        __syncthreads();                          // drains vmcnt -> LDS tile ready
        #pragma unroll
        for (int kk = 0; kk < 2; ++kk) {
            int chunk = kk * 4 + kgrp;
            bf16x8 af[4], bfr[4];
            #pragma unroll
            for (int mi = 0; mi < 4; ++mi) {
                int rl = wr * 64 + mi * 16 + arow;
                af[mi] = *(const bf16x8*)&ldsA[rl * 64 + ((chunk ^ (rl & 7)) * 8)];
            }
            #pragma unroll
            for (int ni = 0; ni < 4; ++ni) {
                int rl = wc * 64 + ni * 16 + arow;
                bfr[ni] = *(const bf16x8*)&ldsB[rl * 64 + ((chunk ^ (rl & 7)) * 8)];
            }
            #pragma unroll
            for (int mi = 0; mi < 4; ++mi)
                #pragma unroll
                for (int ni = 0; ni < 4; ++ni)
                    acc[mi][ni] = __builtin_amdgcn_mfma_f32_16x16x32_bf16(af[mi], bfr[ni], acc[mi][ni], 0, 0, 0);
        }
        __syncthreads();                          // all reads done before next stage
    }
    #pragma unroll
    for (int ni = 0; ni < 4; ++ni) {
        int n = wc * 64 + ni * 16 + arow;
        float bv = EPI_BF16 ? bias[n] : 0.f;
        #pragma unroll
        for (int mi = 0; mi < 4; ++mi)
            #pragma unroll
            for (int r = 0; r < 4; ++r) {
                long m = m0 + wr * 64 + mi * 16 + kgrp * 4 + r;
                if (EPI_BF16)
                    outB[(outRowBase + m) * 256 + n] = f2bf(acc[mi][ni][r] + bv);
                else
                    outF[((long)z * 2048 + m) * 256 + n] = acc[mi][ni][r];
            }
    }
}

// ---------------- reduce partials + bias + leaky ----------------
__global__ __launch_bounds__(256) void reduce2(const float* __restrict__ part,
                                               const float* __restrict__ b2v,
                                               float* __restrict__ out) {
    int l = blockIdx.x, n = threadIdx.x;
    float sum = b2v[n];
    #pragma unroll
    for (int s = 0; s < 8; ++s) sum += part[((size_t)s * 2048 + l) * 256 + n];
    out[(size_t)l * 256 + n] = sum >= 0.f ? sum : 0.01f * sum;
}

extern "C" void kernel_launch(void* const* d_in, const int* in_sizes, int n_in,
                              void* d_out, int out_size, void* d_ws, size_t ws_size,
                              hipStream_t stream) {
    const float* beft = (const float*)d_in[0];
    const float* Wb  = (const float*)d_in[4];
    const float* bb  = (const float*)d_in[5];
    const float* g1  = (const float*)d_in[6];
    const float* b1  = (const float*)d_in[7];
    const float* g2  = (const float*)d_in[8];
    const float* b2  = (const float*)d_in[9];
    const float* c1w = (const float*)d_in[10];
    const float* c1b = (const float*)d_in[11];
    const float* pa  = (const float*)d_in[12];
    const float* c2w = (const float*)d_in[13];
    const float* c2b = (const float*)d_in[14];
    const float* c3w = (const float*)d_in[15];
    const float* c3b = (const float*)d_in[16];
    const float* W1  = (const float*)d_in[17];
    const float* b1v = (const float*)d_in[18];
    const float* W2  = (const float*)d_in[19];
    const float* b2v = (const float*)d_in[20];
    float* out = (float*)d_out;
    char* ws = (char*)d_ws;

    // layout (overlays are temporally disjoint):
    float*          f    = (float*)(ws + 0);                   // 432,000 B [dead after attn]
    float*          cat  = (float*)(ws + 524288);              // 6,048,000 B [dead after conv]
    unsigned short* W1T  = (unsigned short*)(ws + 8388608);    // 524,288 B
    unsigned short* W2T  = (unsigned short*)(ws + 8912896);    // 4,194,304 B
    unsigned short* y1   = (unsigned short*)(ws + 13107200);   // 33,554,432 B
    unsigned short* A2   = (unsigned short*)(ws + 13107200);   // 12,582,912 B [bert phase, overlays y1]
    unsigned short* B2T  = (unsigned short*)(ws + 25690112);   // 393,216 B    [bert phase, within y1]
    float*          bpart= (float*)(ws + 46661632);            // 2,097,152 B  [bert phase]
    unsigned short* Ap   = (unsigned short*)(ws + 46661632);   // Apool chunk [conv/gemm1 phase]
    float*          part = (float*)(ws + 46661632);            // 16,777,216 B [gemm2 phase]

    long avail = (long)ws_size - 46661632L;
    long tpc = avail / (128L * 1024L * 2L);
    if (tpc < 1) tpc = 1;
    if (tpc > 500) tpc = 500;

    split_beft<<<2048, 256, 0, stream>>>(beft, A2);
    b2t_build<<<768, 256, 0, stream>>>(Wb, B2T);
    bert_mfma<<<dim3(16, 4), 256, 0, stream>>>(A2, B2T, bpart);
    bert_reduce<<<L_RES, 64, 0, stream>>>(bpart, bb, f);
    window_attn4<<<500, 256, 0, stream>>>(f, g1, b1, g2, b2, cat);
    transpose_to_bf16<<<dim3(32, 8), 256, 0, stream>>>(W1, W1T, 972, 256, 1024);
    transpose_to_bf16<<<dim3(256, 8), 256, 0, stream>>>(W2, W2T, 8192, 256, 8192);
    zero_pad_rows<<<768, 256, 0, stream>>>((unsigned int*)(y1 + (size_t)2000 * 8192));

    for (long t0 = 0; t0 < 500; t0 += tpc) {
        long nt = (500 - t0 < tpc) ? (500 - t0) : tpc;
        conv_pool<<<(int)(nt * 4), 256, 0, stream>>>(cat, c1w, c1b, pa, c2w, c2b,
                                                     c3w, c3b, Ap, (int)(t0 * 4));
        gemm_tile8<true, 0><<<(int)nt, 512, 0, stream>>>(
            Ap, 1024, W1T, 1024, 16, b1v, y1, nullptr, t0 * 128);
    }
    gemm_tile8<false, 3><<<128, 512, 0, stream>>>(
        y1, 8192, W2T, 8192, 16, nullptr, nullptr, part, 0);
    reduce2<<<L_RES, 256, 0, stream>>>(part, b2v, out);
}

// Round 8
// 159.361 us; speedup vs baseline: 4.7195x; 1.0627x over previous
//
#include <hip/hip_runtime.h>

#define L_RES 2000
#define DF 54
#define WIN 7

typedef short bf16x8 __attribute__((ext_vector_type(8)));
typedef float f32x4 __attribute__((ext_vector_type(4)));
typedef unsigned short ushort8v __attribute__((ext_vector_type(8)));

__device__ __forceinline__ unsigned short f2bf(float f) {
    unsigned int u = __float_as_uint(f);
    unsigned int r = (u + 0x7FFFu + ((u >> 16) & 1u)) >> 16;
    return (unsigned short)r;
}
__device__ __forceinline__ float bf2f(unsigned short h) {
    return __uint_as_float(((unsigned int)h) << 16);
}
// async global->LDS, 16B per lane; LDS dest = wave-uniform base + lane*16
__device__ __forceinline__ void gload16(const unsigned short* g, unsigned short* l) {
    __builtin_amdgcn_global_load_lds(
        (const __attribute__((address_space(1))) void*)g,
        (__attribute__((address_space(3))) void*)l, 16, 0, 0);
}

// ---------------- bert stage a: split beft into A2 = [hi | lo | hi], K=3072, 2048 rows ----------------
__global__ __launch_bounds__(256) void split_beft(const float* __restrict__ beft,
                                                  unsigned short* __restrict__ A2) {
    int l = blockIdx.x;
    int t = threadIdx.x;
    unsigned short* row = A2 + (size_t)l * 3072;
    for (int k = t; k < 1024; k += 256) {
        unsigned short hi = 0, lo = 0;
        if (l < L_RES) {
            float x = beft[(size_t)l * 1024 + k];
            hi = f2bf(x);
            lo = f2bf(x - bf2f(hi));
        }
        row[k] = hi;
        row[1024 + k] = lo;
        row[2048 + k] = hi;
    }
}

// ---------------- bert stage b: B2T[64][3072]: segs {hi,hi,lo} of Wb^T ----------------
__global__ __launch_bounds__(256) void b2t_build(const float* __restrict__ Wb,
                                                 unsigned short* __restrict__ B2T) {
    int idx = blockIdx.x * 256 + threadIdx.x;   // 64*3072 = 196608
    int n = idx / 3072, col = idx % 3072;
    int seg = col >> 10, k = col & 1023;
    unsigned short r = 0;
    if (n < DF) {
        float v = Wb[(size_t)k * DF + n];
        unsigned short hi = f2bf(v);
        r = (seg < 2) ? hi : f2bf(v - bf2f(hi));
    }
    B2T[idx] = r;
}

// ---------------- bert stage c: MFMA GEMM M=2048 N=64, K-split z=4 -> fp32 partials ----------------
__global__ __launch_bounds__(256) void bert_mfma(const unsigned short* __restrict__ A2,
                                                 const unsigned short* __restrict__ B2T,
                                                 float* __restrict__ bpart) {
    __shared__ unsigned short ldsA[128 * 64];
    __shared__ unsigned short ldsB[64 * 64];
    int t = threadIdx.x, w = t >> 6, lane = t & 63;
    int m0 = blockIdx.x * 128;
    int z = blockIdx.y;                       // 4 K-slices of 768
    long koff = (long)z * 768;
    int wr = w >> 1, wc = w & 1;
    int arow = lane & 15, kgrp = lane >> 4;

    const unsigned short* aS[4]; const unsigned short* bS[2];
    int aD[4], bD[2];
    #pragma unroll
    for (int j = 0; j < 4; ++j) {
        int s = j * 256 + t, r = s >> 3, c = s & 7;
        aS[j] = A2 + koff + (size_t)(m0 + r) * 3072 + c * 8;
        aD[j] = r * 64 + ((c ^ (r & 7)) * 8);
    }
    #pragma unroll
    for (int j = 0; j < 2; ++j) {
        int s = j * 256 + t, r = s >> 3, c = s & 7;
        bS[j] = B2T + koff + (size_t)r * 3072 + c * 8;
        bD[j] = r * 64 + ((c ^ (r & 7)) * 8);
    }
    f32x4 acc[4][2];
    #pragma unroll
    for (int mi = 0; mi < 4; ++mi)
        #pragma unroll
        for (int ni = 0; ni < 2; ++ni) acc[mi][ni] = (f32x4)(0.f);

    ushort8v va[4], vb[2];
    #pragma unroll
    for (int j = 0; j < 4; ++j) va[j] = *(const ushort8v*)(aS[j]);
    #pragma unroll
    for (int j = 0; j < 2; ++j) vb[j] = *(const ushort8v*)(bS[j]);

    for (int ks = 0; ks < 12; ++ks) {
        __syncthreads();
        #pragma unroll
        for (int j = 0; j < 4; ++j) *(ushort8v*)&ldsA[aD[j]] = va[j];
        #pragma unroll
        for (int j = 0; j < 2; ++j) *(ushort8v*)&ldsB[bD[j]] = vb[j];
        __syncthreads();
        if (ks + 1 < 12) {
            #pragma unroll
            for (int j = 0; j < 4; ++j) va[j] = *(const ushort8v*)(aS[j] + (ks + 1) * 64);
            #pragma unroll
            for (int j = 0; j < 2; ++j) vb[j] = *(const ushort8v*)(bS[j] + (ks + 1) * 64);
        }
        #pragma unroll
        for (int kk = 0; kk < 2; ++kk) {
            int chunk = kk * 4 + kgrp;
            bf16x8 af[4], bfr[2];
            #pragma unroll
            for (int mi = 0; mi < 4; ++mi) {
                int rl = wr * 64 + mi * 16 + arow;
                af[mi] = *(const bf16x8*)&ldsA[rl * 64 + ((chunk ^ (rl & 7)) * 8)];
            }
            #pragma unroll
            for (int ni = 0; ni < 2; ++ni) {
                int rl = wc * 32 + ni * 16 + arow;
                bfr[ni] = *(const bf16x8*)&ldsB[rl * 64 + ((chunk ^ (rl & 7)) * 8)];
            }
            #pragma unroll
            for (int mi = 0; mi < 4; ++mi)
                #pragma unroll
                for (int ni = 0; ni < 2; ++ni)
                    acc[mi][ni] = __builtin_amdgcn_mfma_f32_16x16x32_bf16(af[mi], bfr[ni], acc[mi][ni], 0, 0, 0);
        }
    }
    #pragma unroll
    for (int ni = 0; ni < 2; ++ni) {
        int n = wc * 32 + ni * 16 + arow;
        #pragma unroll
        for (int mi = 0; mi < 4; ++mi)
            #pragma unroll
            for (int r = 0; r < 4; ++r) {
                int m = m0 + wr * 64 + mi * 16 + kgrp * 4 + r;
                bpart[((size_t)z * 2048 + m) * 64 + n] = acc[mi][ni][r];
            }
    }
}

// ---------------- bert stage d: reduce 4 partials + bias -> f (L,54) ----------------
__global__ __launch_bounds__(64) void bert_reduce(const float* __restrict__ bpart,
                                                  const float* __restrict__ bb,
                                                  float* __restrict__ f) {
    int l = blockIdx.x, n = threadIdx.x;
    if (n < DF) {
        float s = bb[n];
        #pragma unroll
        for (int z = 0; z < 4; ++z) s += bpart[((size_t)z * 2048 + l) * 64 + n];
        f[(size_t)l * DF + n] = s;
    }
}

// ---------------- window gather + attn x2 + concat, 4 residues (1 wave each) ----------------
__device__ __forceinline__ void attn_layer_w(const float (*in)[DF], float (*out)[DF],
                                             float (*s)[WIN][WIN],
                                             const float* __restrict__ g,
                                             const float* __restrict__ b,
                                             float* mm, float* vv, int lane) {
    for (int idx = lane; idx < 3 * WIN * WIN; idx += 64) {
        int h = idx / 49, r = idx % 49, q = r / WIN, k = r % WIN;
        float sum = 0.f;
        #pragma unroll
        for (int d = 0; d < 18; ++d) sum = fmaf(in[q][h * 18 + d], in[k][h * 18 + d], sum);
        s[h][q][k] = sum;
    }
    __syncthreads();
    for (int idx = lane; idx < 3 * WIN; idx += 64) {
        int h = idx / WIN, q = idx % WIN;
        float mx = s[h][q][0];
        #pragma unroll
        for (int k = 1; k < WIN; ++k) mx = fmaxf(mx, s[h][q][k]);
        float e[WIN], sum = 0.f;
        #pragma unroll
        for (int k = 0; k < WIN; ++k) { e[k] = expf(s[h][q][k] - mx); sum += e[k]; }
        float inv = 1.f / sum;
        #pragma unroll
        for (int k = 0; k < WIN; ++k) s[h][q][k] = e[k] * inv;
    }
    __syncthreads();
    for (int idx = lane; idx < WIN * DF; idx += 64) {
        int q = idx / DF, c = idx % DF, h = c / 18;
        float sum = 0.f;
        #pragma unroll
        for (int k = 0; k < WIN; ++k) sum = fmaf(s[h][q][k], in[k][c], sum);
        out[q][c] = sum;
    }
    __syncthreads();
    for (int q = lane; q < WIN; q += 64) {
        float m = 0.f;
        for (int c = 0; c < DF; ++c) m += out[q][c];
        m *= (1.f / DF);
        float v = 0.f;
        for (int c = 0; c < DF; ++c) { float d0 = out[q][c] - m; v = fmaf(d0, d0, v); }
        v *= (1.f / DF);
        mm[q] = m; vv[q] = rsqrtf(v + 1e-5f);
    }
    __syncthreads();
    for (int idx = lane; idx < WIN * DF; idx += 64) {
        int q = idx / DF, c = idx % DF;
        out[q][c] = (out[q][c] - mm[q]) * vv[q] * g[c] + b[c];
    }
    __syncthreads();
}

__global__ __launch_bounds__(256) void window_attn4(const float* __restrict__ f,
                                                    const float* __restrict__ g1,
                                                    const float* __restrict__ b1,
                                                    const float* __restrict__ g2,
                                                    const float* __restrict__ b2,
                                                    float* __restrict__ cat) {
    int wv = threadIdx.x >> 6, lane = threadIdx.x & 63;
    int l = blockIdx.x * 4 + wv;
    __shared__ float w[4][WIN][DF], o1[4][WIN][DF], o2[4][WIN][DF];
    __shared__ float s[4][3][WIN][WIN];
    __shared__ float mm[4][WIN], vvv[4][WIN];
    bool boundary = (l <= WIN) || (l + WIN >= L_RES);
    for (int idx = lane; idx < WIN * DF; idx += 64) {
        int j = idx / DF, d = idx % DF;
        w[wv][j][d] = boundary ? (j == 0 ? f[(size_t)l * DF + d] : 0.f)
                               : f[(size_t)(l - 4 + j) * DF + d];
    }
    __syncthreads();
    attn_layer_w(w[wv], o1[wv], s[wv], g1, b1, mm[wv], vvv[wv], lane);
    attn_layer_w(o1[wv], o2[wv], s[wv], g2, b2, mm[wv], vvv[wv], lane);
    for (int idx = lane; idx < WIN * DF; idx += 64) {
        int j = idx / DF, d = idx % DF;
        cat[(size_t)l * 756 + j * 108 + d] = w[wv][j][d];
        cat[(size_t)l * 756 + j * 108 + DF + d] = o2[wv][j][d];
    }
}

// ---------------- transpose + f32->bf16: dst[n][m], rows m>=M zero-padded ----------------
__global__ __launch_bounds__(256) void transpose_to_bf16(const float* __restrict__ src,
                                                         unsigned short* __restrict__ dst,
                                                         int M, int N, int Mpad) {
    __shared__ float tile[32][33];
    int m0 = blockIdx.x * 32, n0 = blockIdx.y * 32;
    int c = threadIdx.x % 32, r0 = threadIdx.x / 32;
    #pragma unroll
    for (int rr = 0; rr < 4; ++rr) {
        int r = r0 + rr * 8, m = m0 + r;
        tile[r][c] = (m < M) ? src[(size_t)m * N + n0 + c] : 0.f;
    }
    __syncthreads();
    #pragma unroll
    for (int rr = 0; rr < 4; ++rr) {
        int r = r0 + rr * 8;
        dst[(size_t)(n0 + r) * Mpad + m0 + c] = f2bf(tile[c][r]);
    }
}

// zero bf16 y1 pad rows 2000..2047
__global__ __launch_bounds__(256) void zero_pad_rows(unsigned int* __restrict__ p) {
    int i = blockIdx.x * 256 + threadIdx.x;
    if (i < 196608) p[i] = 0u;
}

// ---------------- conv+pool -> Apool[nt*128][1024] bf16 ----------------
// block = 4 residues (one 128-row M-tile). thread = (res, d-pair); channel loop is
// wave-uniform so conv weights are scalar (s_load) and stores are coalesced 4B.
__global__ __launch_bounds__(256) void conv_pool(
        const float* __restrict__ cat,
        const float* __restrict__ c1w, const float* __restrict__ c1b,
        const float* __restrict__ pa_p,
        const float* __restrict__ c2w, const float* __restrict__ c2b,
        const float* __restrict__ c3w, const float* __restrict__ c3b,
        unsigned short* __restrict__ Ap, int lbase) {
    int b = blockIdx.x;
    int l0 = lbase + b * 4;
    int t = threadIdx.x;
    __shared__ float catl[4 * 756];
    for (int i = t; i < 3024; i += 256) catl[i] = cat[(size_t)l0 * 756 + i];
    __syncthreads();
    float pa = pa_p[0];
    unsigned short* base = Ap + (size_t)b * 128 * 1024;
    if (t < 216) {
        int res = t / 54, dp = t - res * 54;
        int d0 = dp * 2;
        const float* cr = catl + res * 756;
        float colA[WIN], colB[WIN];
        #pragma unroll
        for (int h = 0; h < WIN; ++h) {
            colA[h] = cr[h * 108 + d0];
            colB[h] = cr[h * 108 + d0 + 1];
        }
        for (int c = 0; c < 32; ++c) {                    // wave-uniform channel loop
            unsigned short* Arow = base + (size_t)(res * 32 + c) * 1024;
            {   // branch 1: k=3, prelu, pool3 -> 5 outputs
                float w0 = c1w[c * 3], w1 = c1w[c * 3 + 1], w2 = c1w[c * 3 + 2];
                float bb = c1b[c];
                float vA[WIN], vB[WIN];
                #pragma unroll
                for (int h = 0; h < WIN; ++h) {
                    float sA = bb, sB = bb;
                    if (h >= 1) { sA = fmaf(w0, colA[h - 1], sA); sB = fmaf(w0, colB[h - 1], sB); }
                    sA = fmaf(w1, colA[h], sA); sB = fmaf(w1, colB[h], sB);
                    if (h <= 5) { sA = fmaf(w2, colA[h + 1], sA); sB = fmaf(w2, colB[h + 1], sB); }
                    vA[h] = sA >= 0.f ? sA : pa * sA;
                    vB[h] = sB >= 0.f ? sB : pa * sB;
                }
                #pragma unroll
                for (int p = 0; p < 5; ++p) {
                    unsigned int ua = f2bf(fmaxf(fmaxf(vA[p], vA[p + 1]), vA[p + 2]));
                    unsigned int ub = f2bf(fmaxf(fmaxf(vB[p], vB[p + 1]), vB[p + 2]));
                    *(unsigned int*)&Arow[p * 108 + d0] = ua | (ub << 16);
                }
            }
            {   // branch 2: k=5, relu, pool5 -> 3 outputs
                float wg[5], bb = c2b[c];
                #pragma unroll
                for (int x = 0; x < 5; ++x) wg[x] = c2w[c * 5 + x];
                float vA[WIN], vB[WIN];
                #pragma unroll
                for (int h = 0; h < WIN; ++h) {
                    float sA = bb, sB = bb;
                    #pragma unroll
                    for (int x = 0; x < 5; ++x) {
                        int hh = h + x - 2;
                        if (hh >= 0 && hh <= 6) {
                            sA = fmaf(wg[x], colA[hh], sA);
                            sB = fmaf(wg[x], colB[hh], sB);
                        }
                    }
                    vA[h] = fmaxf(sA, 0.f);
                    vB[h] = fmaxf(sB, 0.f);
                }
                #pragma unroll
                for (int p = 0; p < 3; ++p) {
                    float ma = vA[p], mb = vB[p];
                    #pragma unroll
                    for (int r = 1; r < 5; ++r) { ma = fmaxf(ma, vA[p + r]); mb = fmaxf(mb, vB[p + r]); }
                    unsigned int ua = f2bf(ma), ub = f2bf(mb);
                    *(unsigned int*)&Arow[540 + p * 108 + d0] = ua | (ub << 16);
                }
            }
            {   // branch 3: k=7, relu, pool7 -> 1 output
                float wg[7], bb = c3b[c];
                #pragma unroll
                for (int x = 0; x < 7; ++x) wg[x] = c3w[c * 7 + x];
                float ma = 0.f, mb = 0.f;
                #pragma unroll
                for (int h = 0; h < WIN; ++h) {
                    float sA = bb, sB = bb;
                    #pragma unroll
                    for (int x = 0; x < 7; ++x) {
                        int hh = h + x - 3;
                        if (hh >= 0 && hh <= 6) {
                            sA = fmaf(wg[x], colA[hh], sA);
                            sB = fmaf(wg[x], colB[hh], sB);
                        }
                    }
                    ma = fmaxf(ma, sA);
                    mb = fmaxf(mb, sB);
                }
                unsigned int ua = f2bf(fmaxf(ma, 0.f)), ub = f2bf(fmaxf(mb, 0.f));
                *(unsigned int*)&Arow[864 + d0] = ua | (ub << 16);
            }
        }
    }
    // zero K-pad cols 972..1023 for all 128 rows (26 u32 per row)
    for (int i = t; i < 3328; i += 256) {
        int r = i / 26, q = i - r * 26;
        *(unsigned int*)&base[(size_t)r * 1024 + 972 + q * 2] = 0u;
    }
}

// ---------------- 8-wave tiled MFMA GEMM, global_load_lds staging, C[128x256]/block ----------------
// LDS kept LINEAR; the XOR swizzle is applied to the per-lane GLOBAL source column (c^ra,
// an involution) so swizzled ds_read_b128 finds source[r][chunk] at col chunk^(r&7).
template<bool EPI_BF16, int ZBITS>
__global__ __launch_bounds__(512) void gemm_tile8(
        const unsigned short* __restrict__ A, long lda,
        const unsigned short* __restrict__ B, long ldb,
        int nk, const float* __restrict__ bias,
        unsigned short* __restrict__ outB, float* __restrict__ outF,
        long outRowBase) {
    __shared__ unsigned short ldsA[128 * 64];
    __shared__ unsigned short ldsB[256 * 64];
    int t = threadIdx.x, w = t >> 6, lane = t & 63;
    int bid = blockIdx.x;
    int z = bid & ((1 << ZBITS) - 1);
    long m0 = (long)(bid >> ZBITS) * 128;
    long koff = (long)z * (long)nk * 64;
    A += koff; B += koff;
    int wr = w >> 2, wc = w & 3;                 // 2 x 4 wave grid, 64x64 each
    int arow = lane & 15, kgrp = lane >> 4;
    int ra = lane >> 3, cc = lane & 7;
    int csw = (cc ^ ra) * 8;                     // pre-swizzled source column

    const unsigned short* gA[2]; const unsigned short* gB[4];
    unsigned short* dA[2]; unsigned short* dB[4];
    #pragma unroll
    for (int j = 0; j < 2; ++j) {
        int rbase = j * 64 + w * 8;
        gA[j] = A + (size_t)(m0 + rbase + ra) * lda + csw;
        dA[j] = &ldsA[rbase * 64];
    }
    #pragma unroll
    for (int j = 0; j < 4; ++j) {
        int rbase = j * 64 + w * 8;
        gB[j] = B + (size_t)(rbase + ra) * ldb + csw;
        dB[j] = &ldsB[rbase * 64];
    }
    f32x4 acc[4][4];
    #pragma unroll
    for (int mi = 0; mi < 4; ++mi)
        #pragma unroll
        for (int ni = 0; ni < 4; ++ni) acc[mi][ni] = (f32x4)(0.f);

    for (int ks = 0; ks < nk; ++ks) {
        #pragma unroll
        for (int j = 0; j < 2; ++j) gload16(gA[j] + ks * 64, dA[j]);
        #pragma unroll
        for (int j = 0; j < 4; ++j) gload16(gB[j] + ks * 64, dB[j]);
        __syncthreads();                          // drains vmcnt -> LDS tile ready
        #pragma unroll
        for (int kk = 0; kk < 2; ++kk) {
            int chunk = kk * 4 + kgrp;
            bf16x8 af[4], bfr[4];
            #pragma unroll
            for (int mi = 0; mi < 4; ++mi) {
                int rl = wr * 64 + mi * 16 + arow;
                af[mi] = *(const bf16x8*)&ldsA[rl * 64 + ((chunk ^ (rl & 7)) * 8)];
            }
            #pragma unroll
            for (int ni = 0; ni < 4; ++ni) {
                int rl = wc * 64 + ni * 16 + arow;
                bfr[ni] = *(const bf16x8*)&ldsB[rl * 64 + ((chunk ^ (rl & 7)) * 8)];
            }
            #pragma unroll
            for (int mi = 0; mi < 4; ++mi)
                #pragma unroll
                for (int ni = 0; ni < 4; ++ni)
                    acc[mi][ni] = __builtin_amdgcn_mfma_f32_16x16x32_bf16(af[mi], bfr[ni], acc[mi][ni], 0, 0, 0);
        }
        __syncthreads();                          // all reads done before next stage
    }
    #pragma unroll
    for (int ni = 0; ni < 4; ++ni) {
        int n = wc * 64 + ni * 16 + arow;
        float bv = EPI_BF16 ? bias[n] : 0.f;
        #pragma unroll
        for (int mi = 0; mi < 4; ++mi)
            #pragma unroll
            for (int r = 0; r < 4; ++r) {
                long m = m0 + wr * 64 + mi * 16 + kgrp * 4 + r;
                if (EPI_BF16)
                    outB[(outRowBase + m) * 256 + n] = f2bf(acc[mi][ni][r] + bv);
                else
                    outF[((long)z * 2048 + m) * 256 + n] = acc[mi][ni][r];
            }
    }
}

// ---------------- reduce partials + bias + leaky ----------------
__global__ __launch_bounds__(256) void reduce2(const float* __restrict__ part,
                                               const float* __restrict__ b2v,
                                               float* __restrict__ out) {
    int l = blockIdx.x, n = threadIdx.x;
    float sum = b2v[n];
    #pragma unroll
    for (int s = 0; s < 8; ++s) sum += part[((size_t)s * 2048 + l) * 256 + n];
    out[(size_t)l * 256 + n] = sum >= 0.f ? sum : 0.01f * sum;
}

extern "C" void kernel_launch(void* const* d_in, const int* in_sizes, int n_in,
                              void* d_out, int out_size, void* d_ws, size_t ws_size,
                              hipStream_t stream) {
    const float* beft = (const float*)d_in[0];
    const float* Wb  = (const float*)d_in[4];
    const float* bb  = (const float*)d_in[5];
    const float* g1  = (const float*)d_in[6];
    const float* b1  = (const float*)d_in[7];
    const float* g2  = (const float*)d_in[8];
    const float* b2  = (const float*)d_in[9];
    const float* c1w = (const float*)d_in[10];
    const float* c1b = (const float*)d_in[11];
    const float* pa  = (const float*)d_in[12];
    const float* c2w = (const float*)d_in[13];
    const float* c2b = (const float*)d_in[14];
    const float* c3w = (const float*)d_in[15];
    const float* c3b = (const float*)d_in[16];
    const float* W1  = (const float*)d_in[17];
    const float* b1v = (const float*)d_in[18];
    const float* W2  = (const float*)d_in[19];
    const float* b2v = (const float*)d_in[20];
    float* out = (float*)d_out;
    char* ws = (char*)d_ws;

    // layout (overlays are temporally disjoint):
    float*          f    = (float*)(ws + 0);                   // 432,000 B [dead after attn]
    float*          cat  = (float*)(ws + 524288);              // 6,048,000 B [dead after conv]
    unsigned short* W1T  = (unsigned short*)(ws + 8388608);    // 524,288 B
    unsigned short* W2T  = (unsigned short*)(ws + 8912896);    // 4,194,304 B
    unsigned short* y1   = (unsigned short*)(ws + 13107200);   // 33,554,432 B
    unsigned short* A2   = (unsigned short*)(ws + 13107200);   // 12,582,912 B [bert phase, overlays y1]
    unsigned short* B2T  = (unsigned short*)(ws + 25690112);   // 393,216 B    [bert phase, within y1]
    float*          bpart= (float*)(ws + 46661632);            // 2,097,152 B  [bert phase]
    unsigned short* Ap   = (unsigned short*)(ws + 46661632);   // Apool chunk [conv/gemm1 phase]
    float*          part = (float*)(ws + 46661632);            // 16,777,216 B [gemm2 phase]

    long avail = (long)ws_size - 46661632L;
    long tpc = avail / (128L * 1024L * 2L);
    if (tpc < 1) tpc = 1;
    if (tpc > 500) tpc = 500;

    split_beft<<<2048, 256, 0, stream>>>(beft, A2);
    b2t_build<<<768, 256, 0, stream>>>(Wb, B2T);
    bert_mfma<<<dim3(16, 4), 256, 0, stream>>>(A2, B2T, bpart);
    bert_reduce<<<L_RES, 64, 0, stream>>>(bpart, bb, f);
    window_attn4<<<500, 256, 0, stream>>>(f, g1, b1, g2, b2, cat);
    transpose_to_bf16<<<dim3(32, 8), 256, 0, stream>>>(W1, W1T, 972, 256, 1024);
    transpose_to_bf16<<<dim3(256, 8), 256, 0, stream>>>(W2, W2T, 8192, 256, 8192);
    zero_pad_rows<<<768, 256, 0, stream>>>((unsigned int*)(y1 + (size_t)2000 * 8192));

    for (long t0 = 0; t0 < 500; t0 += tpc) {
        long nt = (500 - t0 < tpc) ? (500 - t0) : tpc;
        conv_pool<<<(int)nt, 256, 0, stream>>>(cat, c1w, c1b, pa, c2w, c2b,
                                               c3w, c3b, Ap, (int)(t0 * 4));
        gemm_tile8<true, 0><<<(int)nt, 512, 0, stream>>>(
            Ap, 1024, W1T, 1024, 16, b1v, y1, nullptr, t0 * 128);
    }
    gemm_tile8<false, 3><<<128, 512, 0, stream>>>(
        y1, 8192, W2T, 8192, 16, nullptr, nullptr, part, 0);
    reduce2<<<L_RES, 256, 0, stream>>>(part, b2v, out);
}

// Round 9
// 155.282 us; speedup vs baseline: 4.8435x; 1.0263x over previous
//
#include <hip/hip_runtime.h>

#define L_RES 2000
#define DF 54
#define WIN 7

typedef short bf16x8 __attribute__((ext_vector_type(8)));
typedef float f32x4 __attribute__((ext_vector_type(4)));
typedef unsigned short ushort8v __attribute__((ext_vector_type(8)));

__device__ __forceinline__ unsigned short f2bf(float f) {
    unsigned int u = __float_as_uint(f);
    unsigned int r = (u + 0x7FFFu + ((u >> 16) & 1u)) >> 16;
    return (unsigned short)r;
}
__device__ __forceinline__ float bf2f(unsigned short h) {
    return __uint_as_float(((unsigned int)h) << 16);
}
// async global->LDS, 16B per lane; LDS dest = wave-uniform base + lane*16
__device__ __forceinline__ void gload16(const unsigned short* g, unsigned short* l) {
    __builtin_amdgcn_global_load_lds(
        (const __attribute__((address_space(1))) void*)g,
        (__attribute__((address_space(3))) void*)l, 16, 0, 0);
}

// ---------------- bert stage a: split beft into A2 = [hi | lo | hi], K=3072, 2048 rows ----------------
__global__ __launch_bounds__(256) void split_beft(const float* __restrict__ beft,
                                                  unsigned short* __restrict__ A2) {
    int l = blockIdx.x;
    int t = threadIdx.x;
    unsigned short* row = A2 + (size_t)l * 3072;
    for (int k = t; k < 1024; k += 256) {
        unsigned short hi = 0, lo = 0;
        if (l < L_RES) {
            float x = beft[(size_t)l * 1024 + k];
            hi = f2bf(x);
            lo = f2bf(x - bf2f(hi));
        }
        row[k] = hi;
        row[1024 + k] = lo;
        row[2048 + k] = hi;
    }
}

// ---------------- bert stage b: B2T[64][3072]: segs {hi,hi,lo} of Wb^T ----------------
__global__ __launch_bounds__(256) void b2t_build(const float* __restrict__ Wb,
                                                 unsigned short* __restrict__ B2T) {
    int idx = blockIdx.x * 256 + threadIdx.x;   // 64*3072 = 196608
    int n = idx / 3072, col = idx % 3072;
    int seg = col >> 10, k = col & 1023;
    unsigned short r = 0;
    if (n < DF) {
        float v = Wb[(size_t)k * DF + n];
        unsigned short hi = f2bf(v);
        r = (seg < 2) ? hi : f2bf(v - bf2f(hi));
    }
    B2T[idx] = r;
}

// ---------------- bert stage c: MFMA GEMM M=2048 N=64, K-split z=4 -> fp32 partials ----------------
__global__ __launch_bounds__(256) void bert_mfma(const unsigned short* __restrict__ A2,
                                                 const unsigned short* __restrict__ B2T,
                                                 float* __restrict__ bpart) {
    __shared__ unsigned short ldsA[128 * 64];
    __shared__ unsigned short ldsB[64 * 64];
    int t = threadIdx.x, w = t >> 6, lane = t & 63;
    int m0 = blockIdx.x * 128;
    int z = blockIdx.y;                       // 4 K-slices of 768
    long koff = (long)z * 768;
    int wr = w >> 1, wc = w & 1;
    int arow = lane & 15, kgrp = lane >> 4;

    const unsigned short* aS[4]; const unsigned short* bS[2];
    int aD[4], bD[2];
    #pragma unroll
    for (int j = 0; j < 4; ++j) {
        int s = j * 256 + t, r = s >> 3, c = s & 7;
        aS[j] = A2 + koff + (size_t)(m0 + r) * 3072 + c * 8;
        aD[j] = r * 64 + ((c ^ (r & 7)) * 8);
    }
    #pragma unroll
    for (int j = 0; j < 2; ++j) {
        int s = j * 256 + t, r = s >> 3, c = s & 7;
        bS[j] = B2T + koff + (size_t)r * 3072 + c * 8;
        bD[j] = r * 64 + ((c ^ (r & 7)) * 8);
    }
    f32x4 acc[4][2];
    #pragma unroll
    for (int mi = 0; mi < 4; ++mi)
        #pragma unroll
        for (int ni = 0; ni < 2; ++ni) acc[mi][ni] = (f32x4)(0.f);

    ushort8v va[4], vb[2];
    #pragma unroll
    for (int j = 0; j < 4; ++j) va[j] = *(const ushort8v*)(aS[j]);
    #pragma unroll
    for (int j = 0; j < 2; ++j) vb[j] = *(const ushort8v*)(bS[j]);

    for (int ks = 0; ks < 12; ++ks) {
        __syncthreads();
        #pragma unroll
        for (int j = 0; j < 4; ++j) *(ushort8v*)&ldsA[aD[j]] = va[j];
        #pragma unroll
        for (int j = 0; j < 2; ++j) *(ushort8v*)&ldsB[bD[j]] = vb[j];
        __syncthreads();
        if (ks + 1 < 12) {
            #pragma unroll
            for (int j = 0; j < 4; ++j) va[j] = *(const ushort8v*)(aS[j] + (ks + 1) * 64);
            #pragma unroll
            for (int j = 0; j < 2; ++j) vb[j] = *(const ushort8v*)(bS[j] + (ks + 1) * 64);
        }
        #pragma unroll
        for (int kk = 0; kk < 2; ++kk) {
            int chunk = kk * 4 + kgrp;
            bf16x8 af[4], bfr[2];
            #pragma unroll
            for (int mi = 0; mi < 4; ++mi) {
                int rl = wr * 64 + mi * 16 + arow;
                af[mi] = *(const bf16x8*)&ldsA[rl * 64 + ((chunk ^ (rl & 7)) * 8)];
            }
            #pragma unroll
            for (int ni = 0; ni < 2; ++ni) {
                int rl = wc * 32 + ni * 16 + arow;
                bfr[ni] = *(const bf16x8*)&ldsB[rl * 64 + ((chunk ^ (rl & 7)) * 8)];
            }
            #pragma unroll
            for (int mi = 0; mi < 4; ++mi)
                #pragma unroll
                for (int ni = 0; ni < 2; ++ni)
                    acc[mi][ni] = __builtin_amdgcn_mfma_f32_16x16x32_bf16(af[mi], bfr[ni], acc[mi][ni], 0, 0, 0);
        }
    }
    #pragma unroll
    for (int ni = 0; ni < 2; ++ni) {
        int n = wc * 32 + ni * 16 + arow;
        #pragma unroll
        for (int mi = 0; mi < 4; ++mi)
            #pragma unroll
            for (int r = 0; r < 4; ++r) {
                int m = m0 + wr * 64 + mi * 16 + kgrp * 4 + r;
                bpart[((size_t)z * 2048 + m) * 64 + n] = acc[mi][ni][r];
            }
    }
}

// ---------------- bert stage d: reduce 4 partials + bias -> f (L,54) ----------------
__global__ __launch_bounds__(64) void bert_reduce(const float* __restrict__ bpart,
                                                  const float* __restrict__ bb,
                                                  float* __restrict__ f) {
    int l = blockIdx.x, n = threadIdx.x;
    if (n < DF) {
        float s = bb[n];
        #pragma unroll
        for (int z = 0; z < 4; ++z) s += bpart[((size_t)z * 2048 + l) * 64 + n];
        f[(size_t)l * DF + n] = s;
    }
}

// ---------------- window gather + attn x2 + concat, 4 residues (1 wave each) ----------------
__device__ __forceinline__ void attn_layer_w(const float (*in)[DF], float (*out)[DF],
                                             float (*s)[WIN][WIN],
                                             const float* __restrict__ g,
                                             const float* __restrict__ b,
                                             float* mm, float* vv, int lane) {
    for (int idx = lane; idx < 3 * WIN * WIN; idx += 64) {
        int h = idx / 49, r = idx % 49, q = r / WIN, k = r % WIN;
        float sum = 0.f;
        #pragma unroll
        for (int d = 0; d < 18; ++d) sum = fmaf(in[q][h * 18 + d], in[k][h * 18 + d], sum);
        s[h][q][k] = sum;
    }
    __syncthreads();
    for (int idx = lane; idx < 3 * WIN; idx += 64) {
        int h = idx / WIN, q = idx % WIN;
        float mx = s[h][q][0];
        #pragma unroll
        for (int k = 1; k < WIN; ++k) mx = fmaxf(mx, s[h][q][k]);
        float e[WIN], sum = 0.f;
        #pragma unroll
        for (int k = 0; k < WIN; ++k) { e[k] = expf(s[h][q][k] - mx); sum += e[k]; }
        float inv = 1.f / sum;
        #pragma unroll
        for (int k = 0; k < WIN; ++k) s[h][q][k] = e[k] * inv;
    }
    __syncthreads();
    for (int idx = lane; idx < WIN * DF; idx += 64) {
        int q = idx / DF, c = idx % DF, h = c / 18;
        float sum = 0.f;
        #pragma unroll
        for (int k = 0; k < WIN; ++k) sum = fmaf(s[h][q][k], in[k][c], sum);
        out[q][c] = sum;
    }
    __syncthreads();
    for (int q = lane; q < WIN; q += 64) {
        float m = 0.f;
        for (int c = 0; c < DF; ++c) m += out[q][c];
        m *= (1.f / DF);
        float v = 0.f;
        for (int c = 0; c < DF; ++c) { float d0 = out[q][c] - m; v = fmaf(d0, d0, v); }
        v *= (1.f / DF);
        mm[q] = m; vv[q] = rsqrtf(v + 1e-5f);
    }
    __syncthreads();
    for (int idx = lane; idx < WIN * DF; idx += 64) {
        int q = idx / DF, c = idx % DF;
        out[q][c] = (out[q][c] - mm[q]) * vv[q] * g[c] + b[c];
    }
    __syncthreads();
}

__global__ __launch_bounds__(256) void window_attn4(const float* __restrict__ f,
                                                    const float* __restrict__ g1,
                                                    const float* __restrict__ b1,
                                                    const float* __restrict__ g2,
                                                    const float* __restrict__ b2,
                                                    float* __restrict__ cat) {
    int wv = threadIdx.x >> 6, lane = threadIdx.x & 63;
    int l = blockIdx.x * 4 + wv;
    __shared__ float w[4][WIN][DF], o1[4][WIN][DF], o2[4][WIN][DF];
    __shared__ float s[4][3][WIN][WIN];
    __shared__ float mm[4][WIN], vvv[4][WIN];
    bool boundary = (l <= WIN) || (l + WIN >= L_RES);
    for (int idx = lane; idx < WIN * DF; idx += 64) {
        int j = idx / DF, d = idx % DF;
        w[wv][j][d] = boundary ? (j == 0 ? f[(size_t)l * DF + d] : 0.f)
                               : f[(size_t)(l - 4 + j) * DF + d];
    }
    __syncthreads();
    attn_layer_w(w[wv], o1[wv], s[wv], g1, b1, mm[wv], vvv[wv], lane);
    attn_layer_w(o1[wv], o2[wv], s[wv], g2, b2, mm[wv], vvv[wv], lane);
    for (int idx = lane; idx < WIN * DF; idx += 64) {
        int j = idx / DF, d = idx % DF;
        cat[(size_t)l * 756 + j * 108 + d] = w[wv][j][d];
        cat[(size_t)l * 756 + j * 108 + DF + d] = o2[wv][j][d];
    }
}

// ---------------- transpose + f32->bf16: dst[n][m], rows m>=M zero-padded ----------------
__global__ __launch_bounds__(256) void transpose_to_bf16(const float* __restrict__ src,
                                                         unsigned short* __restrict__ dst,
                                                         int M, int N, int Mpad) {
    __shared__ float tile[32][33];
    int m0 = blockIdx.x * 32, n0 = blockIdx.y * 32;
    int c = threadIdx.x % 32, r0 = threadIdx.x / 32;
    #pragma unroll
    for (int rr = 0; rr < 4; ++rr) {
        int r = r0 + rr * 8, m = m0 + r;
        tile[r][c] = (m < M) ? src[(size_t)m * N + n0 + c] : 0.f;
    }
    __syncthreads();
    #pragma unroll
    for (int rr = 0; rr < 4; ++rr) {
        int r = r0 + rr * 8;
        dst[(size_t)(n0 + r) * Mpad + m0 + c] = f2bf(tile[c][r]);
    }
}

// ---------------- conv+pool -> Apool[nt*128][1024] bf16 ----------------
// grid = nt*2: b = bid>>1 (M-tile of 4 residues), ch-half = (bid&1)*16.
// wave = one residue (res = t>>6, dp = t&63<54); channel loop wave-uniform ->
// scalar weight loads; per-(c,p) store = one contiguous 216B run per wave.
__global__ __launch_bounds__(256) void conv_pool(
        const float* __restrict__ cat,
        const float* __restrict__ c1w, const float* __restrict__ c1b,
        const float* __restrict__ pa_p,
        const float* __restrict__ c2w, const float* __restrict__ c2b,
        const float* __restrict__ c3w, const float* __restrict__ c3b,
        unsigned short* __restrict__ Ap, int lbase) {
    int bid = blockIdx.x;
    int b = bid >> 1;
    int ch0 = (bid & 1) * 16;
    int l0 = lbase + b * 4;
    int t = threadIdx.x;
    __shared__ float catl[4 * 756];
    for (int i = t; i < 3024; i += 256) catl[i] = cat[(size_t)l0 * 756 + i];
    __syncthreads();
    float pa = pa_p[0];
    unsigned short* base = Ap + (size_t)b * 128 * 1024;
    int res = t >> 6, dp = t & 63;
    if (dp < 54) {
        int d0 = dp * 2;
        const float* cr = catl + res * 756;
        float colA[WIN], colB[WIN];
        #pragma unroll
        for (int h = 0; h < WIN; ++h) {
            colA[h] = cr[h * 108 + d0];
            colB[h] = cr[h * 108 + d0 + 1];
        }
        for (int c = ch0; c < ch0 + 16; ++c) {            // wave-uniform channel loop
            unsigned short* Arow = base + (size_t)(res * 32 + c) * 1024;
            {   // branch 1: k=3, prelu, pool3 -> 5 outputs
                float w0 = c1w[c * 3], w1 = c1w[c * 3 + 1], w2 = c1w[c * 3 + 2];
                float bb = c1b[c];
                float vA[WIN], vB[WIN];
                #pragma unroll
                for (int h = 0; h < WIN; ++h) {
                    float sA = bb, sB = bb;
                    if (h >= 1) { sA = fmaf(w0, colA[h - 1], sA); sB = fmaf(w0, colB[h - 1], sB); }
                    sA = fmaf(w1, colA[h], sA); sB = fmaf(w1, colB[h], sB);
                    if (h <= 5) { sA = fmaf(w2, colA[h + 1], sA); sB = fmaf(w2, colB[h + 1], sB); }
                    vA[h] = sA >= 0.f ? sA : pa * sA;
                    vB[h] = sB >= 0.f ? sB : pa * sB;
                }
                #pragma unroll
                for (int p = 0; p < 5; ++p) {
                    unsigned int ua = f2bf(fmaxf(fmaxf(vA[p], vA[p + 1]), vA[p + 2]));
                    unsigned int ub = f2bf(fmaxf(fmaxf(vB[p], vB[p + 1]), vB[p + 2]));
                    *(unsigned int*)&Arow[p * 108 + d0] = ua | (ub << 16);
                }
            }
            {   // branch 2: k=5, relu, pool5 -> 3 outputs
                float wg[5], bb = c2b[c];
                #pragma unroll
                for (int x = 0; x < 5; ++x) wg[x] = c2w[c * 5 + x];
                float vA[WIN], vB[WIN];
                #pragma unroll
                for (int h = 0; h < WIN; ++h) {
                    float sA = bb, sB = bb;
                    #pragma unroll
                    for (int x = 0; x < 5; ++x) {
                        int hh = h + x - 2;
                        if (hh >= 0 && hh <= 6) {
                            sA = fmaf(wg[x], colA[hh], sA);
                            sB = fmaf(wg[x], colB[hh], sB);
                        }
                    }
                    vA[h] = fmaxf(sA, 0.f);
                    vB[h] = fmaxf(sB, 0.f);
                }
                #pragma unroll
                for (int p = 0; p < 3; ++p) {
                    float ma = vA[p], mb = vB[p];
                    #pragma unroll
                    for (int r = 1; r < 5; ++r) { ma = fmaxf(ma, vA[p + r]); mb = fmaxf(mb, vB[p + r]); }
                    unsigned int ua = f2bf(ma), ub = f2bf(mb);
                    *(unsigned int*)&Arow[540 + p * 108 + d0] = ua | (ub << 16);
                }
            }
            {   // branch 3: k=7, relu, pool7 -> 1 output
                float wg[7], bb = c3b[c];
                #pragma unroll
                for (int x = 0; x < 7; ++x) wg[x] = c3w[c * 7 + x];
                float ma = 0.f, mb = 0.f;
                #pragma unroll
                for (int h = 0; h < WIN; ++h) {
                    float sA = bb, sB = bb;
                    #pragma unroll
                    for (int x = 0; x < 7; ++x) {
                        int hh = h + x - 3;
                        if (hh >= 0 && hh <= 6) {
                            sA = fmaf(wg[x], colA[hh], sA);
                            sB = fmaf(wg[x], colB[hh], sB);
                        }
                    }
                    ma = fmaxf(ma, sA);
                    mb = fmaxf(mb, sB);
                }
                unsigned int ua = f2bf(fmaxf(ma, 0.f)), ub = f2bf(fmaxf(mb, 0.f));
                *(unsigned int*)&Arow[864 + d0] = ua | (ub << 16);
            }
        }
    }
    // zero K-pad cols 972..1023 for this block's 64 rows (26 u32 per row)
    for (int i = t; i < 1664; i += 256) {
        int r = i / 26, q = i - r * 26;           // r in 0..63
        int res2 = r >> 4, c2 = ch0 + (r & 15);
        *(unsigned int*)&base[(size_t)(res2 * 32 + c2) * 1024 + 972 + q * 2] = 0u;
    }
}

// ---------------- 8-wave tiled MFMA GEMM, global_load_lds staging, C[128x256]/block ----------------
// LDS kept LINEAR; the XOR swizzle is applied to the per-lane GLOBAL source column (c^ra,
// an involution) so swizzled ds_read_b128 finds source[r][chunk] at col chunk^(r&7).
template<bool EPI_BF16, int ZBITS>
__global__ __launch_bounds__(512) void gemm_tile8(
        const unsigned short* __restrict__ A, long lda,
        const unsigned short* __restrict__ B, long ldb,
        int nk, const float* __restrict__ bias,
        unsigned short* __restrict__ outB, float* __restrict__ outF,
        long outRowBase) {
    __shared__ unsigned short ldsA[128 * 64];
    __shared__ unsigned short ldsB[256 * 64];
    int t = threadIdx.x, w = t >> 6, lane = t & 63;
    int bid = blockIdx.x;
    int z = bid & ((1 << ZBITS) - 1);
    long m0 = (long)(bid >> ZBITS) * 128;
    long koff = (long)z * (long)nk * 64;
    A += koff; B += koff;
    int wr = w >> 2, wc = w & 3;                 // 2 x 4 wave grid, 64x64 each
    int arow = lane & 15, kgrp = lane >> 4;
    int ra = lane >> 3, cc = lane & 7;
    int csw = (cc ^ ra) * 8;                     // pre-swizzled source column

    const unsigned short* gA[2]; const unsigned short* gB[4];
    unsigned short* dA[2]; unsigned short* dB[4];
    #pragma unroll
    for (int j = 0; j < 2; ++j) {
        int rbase = j * 64 + w * 8;
        gA[j] = A + (size_t)(m0 + rbase + ra) * lda + csw;
        dA[j] = &ldsA[rbase * 64];
    }
    #pragma unroll
    for (int j = 0; j < 4; ++j) {
        int rbase = j * 64 + w * 8;
        gB[j] = B + (size_t)(rbase + ra) * ldb + csw;
        dB[j] = &ldsB[rbase * 64];
    }
    f32x4 acc[4][4];
    #pragma unroll
    for (int mi = 0; mi < 4; ++mi)
        #pragma unroll
        for (int ni = 0; ni < 4; ++ni) acc[mi][ni] = (f32x4)(0.f);

    for (int ks = 0; ks < nk; ++ks) {
        #pragma unroll
        for (int j = 0; j < 2; ++j) gload16(gA[j] + ks * 64, dA[j]);
        #pragma unroll
        for (int j = 0; j < 4; ++j) gload16(gB[j] + ks * 64, dB[j]);
        __syncthreads();                          // drains vmcnt -> LDS tile ready
        #pragma unroll
        for (int kk = 0; kk < 2; ++kk) {
            int chunk = kk * 4 + kgrp;
            bf16x8 af[4], bfr[4];
            #pragma unroll
            for (int mi = 0; mi < 4; ++mi) {
                int rl = wr * 64 + mi * 16 + arow;
                af[mi] = *(const bf16x8*)&ldsA[rl * 64 + ((chunk ^ (rl & 7)) * 8)];
            }
            #pragma unroll
            for (int ni = 0; ni < 4; ++ni) {
                int rl = wc * 64 + ni * 16 + arow;
                bfr[ni] = *(const bf16x8*)&ldsB[rl * 64 + ((chunk ^ (rl & 7)) * 8)];
            }
            #pragma unroll
            for (int mi = 0; mi < 4; ++mi)
                #pragma unroll
                for (int ni = 0; ni < 4; ++ni)
                    acc[mi][ni] = __builtin_amdgcn_mfma_f32_16x16x32_bf16(af[mi], bfr[ni], acc[mi][ni], 0, 0, 0);
        }
        __syncthreads();                          // all reads done before next stage
    }
    #pragma unroll
    for (int ni = 0; ni < 4; ++ni) {
        int n = wc * 64 + ni * 16 + arow;
        float bv = EPI_BF16 ? bias[n] : 0.f;
        #pragma unroll
        for (int mi = 0; mi < 4; ++mi)
            #pragma unroll
            for (int r = 0; r < 4; ++r) {
                long m = m0 + wr * 64 + mi * 16 + kgrp * 4 + r;
                if (EPI_BF16)
                    outB[(outRowBase + m) * 256 + n] = f2bf(acc[mi][ni][r] + bv);
                else
                    outF[((long)z * 2048 + m) * 256 + n] = acc[mi][ni][r];
            }
    }
}

// ---------------- reduce partials + bias + leaky ----------------
__global__ __launch_bounds__(256) void reduce2(const float* __restrict__ part,
                                               const float* __restrict__ b2v,
                                               float* __restrict__ out) {
    int l = blockIdx.x, n = threadIdx.x;
    float sum = b2v[n];
    #pragma unroll
    for (int s = 0; s < 8; ++s) sum += part[((size_t)s * 2048 + l) * 256 + n];
    out[(size_t)l * 256 + n] = sum >= 0.f ? sum : 0.01f * sum;
}

extern "C" void kernel_launch(void* const* d_in, const int* in_sizes, int n_in,
                              void* d_out, int out_size, void* d_ws, size_t ws_size,
                              hipStream_t stream) {
    const float* beft = (const float*)d_in[0];
    const float* Wb  = (const float*)d_in[4];
    const float* bb  = (const float*)d_in[5];
    const float* g1  = (const float*)d_in[6];
    const float* b1  = (const float*)d_in[7];
    const float* g2  = (const float*)d_in[8];
    const float* b2  = (const float*)d_in[9];
    const float* c1w = (const float*)d_in[10];
    const float* c1b = (const float*)d_in[11];
    const float* pa  = (const float*)d_in[12];
    const float* c2w = (const float*)d_in[13];
    const float* c2b = (const float*)d_in[14];
    const float* c3w = (const float*)d_in[15];
    const float* c3b = (const float*)d_in[16];
    const float* W1  = (const float*)d_in[17];
    const float* b1v = (const float*)d_in[18];
    const float* W2  = (const float*)d_in[19];
    const float* b2v = (const float*)d_in[20];
    float* out = (float*)d_out;
    char* ws = (char*)d_ws;

    // layout (overlays are temporally disjoint):
    float*          f    = (float*)(ws + 0);                   // 432,000 B [dead after attn]
    float*          cat  = (float*)(ws + 524288);              // 6,048,000 B [dead after conv]
    unsigned short* W1T  = (unsigned short*)(ws + 8388608);    // 524,288 B
    unsigned short* W2T  = (unsigned short*)(ws + 8912896);    // 4,194,304 B
    unsigned short* y1   = (unsigned short*)(ws + 13107200);   // 33,554,432 B
    unsigned short* A2   = (unsigned short*)(ws + 13107200);   // 12,582,912 B [bert phase, overlays y1]
    unsigned short* B2T  = (unsigned short*)(ws + 25690112);   // 393,216 B    [bert phase, within y1]
    float*          bpart= (float*)(ws + 46661632);            // 2,097,152 B  [bert phase]
    unsigned short* Ap   = (unsigned short*)(ws + 46661632);   // Apool chunk [conv/gemm1 phase]
    float*          part = (float*)(ws + 46661632);            // 16,777,216 B [gemm2 phase]

    long avail = (long)ws_size - 46661632L;
    long tpc = avail / (128L * 1024L * 2L);
    if (tpc < 1) tpc = 1;
    if (tpc > 500) tpc = 500;

    split_beft<<<2048, 256, 0, stream>>>(beft, A2);
    b2t_build<<<768, 256, 0, stream>>>(Wb, B2T);
    bert_mfma<<<dim3(16, 4), 256, 0, stream>>>(A2, B2T, bpart);
    bert_reduce<<<L_RES, 64, 0, stream>>>(bpart, bb, f);
    window_attn4<<<500, 256, 0, stream>>>(f, g1, b1, g2, b2, cat);
    transpose_to_bf16<<<dim3(32, 8), 256, 0, stream>>>(W1, W1T, 972, 256, 1024);
    transpose_to_bf16<<<dim3(256, 8), 256, 0, stream>>>(W2, W2T, 8192, 256, 8192);
    // note: y1 pad rows 2000..2047 intentionally NOT zeroed — gemm2 garbage from
    // those A-rows lands only in part rows >=2000, which reduce2 never reads.

    for (long t0 = 0; t0 < 500; t0 += tpc) {
        long nt = (500 - t0 < tpc) ? (500 - t0) : tpc;
        conv_pool<<<(int)(nt * 2), 256, 0, stream>>>(cat, c1w, c1b, pa, c2w, c2b,
                                                     c3w, c3b, Ap, (int)(t0 * 4));
        gemm_tile8<true, 0><<<(int)nt, 512, 0, stream>>>(
            Ap, 1024, W1T, 1024, 16, b1v, y1, nullptr, t0 * 128);
    }
    gemm_tile8<false, 3><<<128, 512, 0, stream>>>(
        y1, 8192, W2T, 8192, 16, nullptr, nullptr, part, 0);
    reduce2<<<L_RES, 256, 0, stream>>>(part, b2v, out);
}